// Round 4
// baseline (338.004 us; speedup 1.0000x reference)
//
#include <hip/hip_runtime.h>

// DIM=256 H=8 HD=32 W=64 N=8192 nw=128
// xyz: T=40, off=20, hi=39, R=120 (pad 128) ; rgb: T=32, off=16, hi=31, R=96
// table element ((c*T+t)*8+h)*32+d == r*256 + h*32 + d, r=c*T+t
// table sizes: xyz 120*256 = 30,720 el = 7,680 float4 ; rgb 96*256 = 24,576 el = 6,144 float4

typedef __attribute__((ext_vector_type(8))) short short8;
typedef __attribute__((ext_vector_type(4))) float f32x4;

__device__ __forceinline__ unsigned short f2bf(float f) {
    union { float f; unsigned int u; } v; v.f = f;
    unsigned int r = v.u + 0x7FFFu + ((v.u >> 16) & 1u);
    return (unsigned short)(r >> 16);
}

// ---------------------------------------------------------------------------
// Cast prepass: fp32 -> bf16 for feats, qkv_w, proj_w, 6 tables.
// float4-index boundaries (exact): 524288 / 49152 / 16384 / 3x7680 / 3x6144,
// total 631,296 float4 -> grid 2466 x 256.
// ---------------------------------------------------------------------------
__global__ __launch_bounds__(256) void k_cast(
    const float* __restrict__ s0, const float* __restrict__ s1,
    const float* __restrict__ s2, const float* __restrict__ s3,
    const float* __restrict__ s4, const float* __restrict__ s5,
    const float* __restrict__ s6, const float* __restrict__ s7,
    const float* __restrict__ s8, ushort* __restrict__ dst)
{
    unsigned g = blockIdx.x * 256 + threadIdx.x;   // float4 index, < 631296
    const float* src;
    unsigned base;
    if      (g < 524288u) { src = s0; base = 0; }
    else if (g < 573440u) { src = s1; base = 524288u; }
    else if (g < 589824u) { src = s2; base = 573440u; }
    else if (g < 597504u) { src = s3; base = 589824u; }
    else if (g < 605184u) { src = s4; base = 597504u; }
    else if (g < 612864u) { src = s5; base = 605184u; }
    else if (g < 619008u) { src = s6; base = 612864u; }
    else if (g < 625152u) { src = s7; base = 619008u; }
    else                  { src = s8; base = 625152u; }
    float4 v = *(const float4*)(src + (size_t)(g - base) * 4);
    ushort4 o;
    o.x = f2bf(v.x); o.y = f2bf(v.y); o.z = f2bf(v.z); o.w = f2bf(v.w);
    *(ushort4*)(dst + (size_t)g * 4) = o;
}

// ---------------------------------------------------------------------------
// QKV GEMM (bf16 MFMA): qkv = feats @ qkv_w^T + b -> q/k/v bf16 [nw][H][W][HD]
// Tile 128x64, 4 waves 2x2, K-chunks of 64.
// ---------------------------------------------------------------------------
__global__ __launch_bounds__(256) void k_qkv(
    const ushort* __restrict__ A, const ushort* __restrict__ B,
    const float* __restrict__ bias,
    ushort* __restrict__ qb, ushort* __restrict__ kb, ushort* __restrict__ vb)
{
    __shared__ __align__(16) ushort a_s[128 * 72];
    __shared__ __align__(16) ushort b_s[64 * 72];
    const int tid = threadIdx.x;
    const int m0 = blockIdx.y * 128;
    const int n0 = blockIdx.x * 64;
    const int w = tid >> 6, wm = w >> 1, wn = w & 1;
    const int l4 = tid & 15, quad = (tid >> 4) & 3;
    f32x4 acc[4][2];
#pragma unroll
    for (int mt = 0; mt < 4; ++mt)
#pragma unroll
        for (int nt = 0; nt < 2; ++nt) acc[mt][nt] = (f32x4){0.f, 0.f, 0.f, 0.f};

    for (int k0 = 0; k0 < 256; k0 += 64) {
#pragma unroll
        for (int l = 0; l < 4; ++l) {
            int e = tid + l * 256;
            int row = e >> 3, kq = e & 7;
            *(uint4*)&a_s[row * 72 + kq * 8] =
                *(const uint4*)(A + (size_t)(m0 + row) * 256 + k0 + kq * 8);
        }
#pragma unroll
        for (int l = 0; l < 2; ++l) {
            int e = tid + l * 256;
            int row = e >> 3, kq = e & 7;
            *(uint4*)&b_s[row * 72 + kq * 8] =
                *(const uint4*)(B + (size_t)(n0 + row) * 256 + k0 + kq * 8);
        }
        __syncthreads();
#pragma unroll
        for (int kh = 0; kh < 2; ++kh) {
            short8 bf0 = *(const short8*)&b_s[(wn * 32 + l4) * 72 + kh * 32 + quad * 8];
            short8 bf1 = *(const short8*)&b_s[(wn * 32 + 16 + l4) * 72 + kh * 32 + quad * 8];
#pragma unroll
            for (int mt = 0; mt < 4; ++mt) {
                short8 af = *(const short8*)&a_s[(wm * 64 + mt * 16 + l4) * 72 + kh * 32 + quad * 8];
                acc[mt][0] = __builtin_amdgcn_mfma_f32_16x16x32_bf16(af, bf0, acc[mt][0], 0, 0, 0);
                acc[mt][1] = __builtin_amdgcn_mfma_f32_16x16x32_bf16(af, bf1, acc[mt][1], 0, 0, 0);
            }
        }
        __syncthreads();
    }
#pragma unroll
    for (int nt = 0; nt < 2; ++nt) {
        int c = n0 + wn * 32 + nt * 16 + l4;
        float bv = bias[c];
        int s = c >> 8, rem = c & 255, h = rem >> 5, d = rem & 31;
        ushort* dst = (s == 0) ? qb : ((s == 1) ? kb : vb);
        float mul = (s == 0) ? 0.17677669529663687f : 1.0f;
#pragma unroll
        for (int mt = 0; mt < 4; ++mt) {
            int mbase = m0 + wm * 64 + mt * 16 + quad * 4;
#pragma unroll
            for (int reg = 0; reg < 4; ++reg) {
                int m = mbase + reg;
                int nw = m >> 6, ii = m & 63;
                dst[((size_t)((nw * 8 + h) * 64 + ii)) * 32 + d] = f2bf((acc[mt][nt][reg] + bv) * mul);
            }
        }
    }
}

// ---------------------------------------------------------------------------
// MFMA attention per (window, head). 4 waves; wave w owns rows w*16..w*16+15.
// A/B frag: [outer=lane&15][k=quad*8+j] ; C/D: col=lane&15, row=quad*4+reg.
// LDS: dbuf fp32 64x122 (31,232 B) + ushort union U (22,528 B) = 53,760 B
// -> 3 blocks/CU.
// ---------------------------------------------------------------------------
#define DBS 122

__global__ __launch_bounds__(256, 3) void k_attn(
    const ushort* __restrict__ qb, const ushort* __restrict__ kb, const ushort* __restrict__ vb,
    const float* __restrict__ nco,
    const ushort* __restrict__ qxt, const ushort* __restrict__ kxt, const ushort* __restrict__ vxt,
    const ushort* __restrict__ qrt, const ushort* __restrict__ krt, const ushort* __restrict__ vrt,
    ushort* __restrict__ aout)
{
    __shared__ __align__(16) float dbuf[64 * DBS];
    __shared__ __align__(16) ushort U[11264];
    // Phase A overlays:
    ushort* q_s  = U;              // [64][40]
    ushort* k_s  = U + 2560;       // [64][40]
    ushort* tbl  = U + 5120;       // [128][40]
    float*  cwf  = (float*)(U + 10240);  // [64][6], dead after idx precompute
    // Phase B overlays:
    ushort* attn_s = U;            // [64][72]
    ushort* v_t    = U + 4608;     // [32][72]
    ushort* vtbl   = U + 6912;     // [32][136]

    const int tid = threadIdx.x;
    const int n = blockIdx.x >> 3;
    const int h = blockIdx.x & 7;
    const int w = tid >> 6;
    const int l4 = tid & 15;
    const int quad = (tid >> 4) & 3;

    const size_t base = (size_t)((n * 8 + h) * 64) * 32;

    // ---- stage q, k, coords, tbl(kx) ----
    {
        int row = tid >> 2, part = tid & 3;
        *(uint4*)&q_s[row * 40 + part * 8] = *(const uint4*)(qb + base + tid * 8);
        *(uint4*)&k_s[row * 40 + part * 8] = *(const uint4*)(kb + base + tid * 8);
    }
    if (tid < 64) {
        const float* cp = nco + (size_t)(n * 64 + tid) * 6;
        cwf[tid * 6 + 0] = cp[0] * 4.f; cwf[tid * 6 + 1] = cp[1] * 4.f;
        cwf[tid * 6 + 2] = cp[2] * 4.f; cwf[tid * 6 + 3] = cp[3] * 8.f;
        cwf[tid * 6 + 4] = cp[4] * 8.f; cwf[tid * 6 + 5] = cp[5] * 8.f;
    }

    auto stageTbl = [&](const ushort* tbg, int R, int Rpad) {
        int r = tid >> 1, half = tid & 1;
        if (r < R) {
            const ushort* src = tbg + (size_t)r * 256 + half * 16;
            ushort* dp = &tbl[r * 40 + half * 16];
            *(uint4*)dp = *(const uint4*)src;
            *(uint4*)(dp + 8) = *(const uint4*)(src + 8);
        }
        for (int e = tid; e < (Rpad - R) * 40; e += 256) tbl[R * 40 + e] = 0;
    };
    auto stageVtbl = [&](const ushort* tbg, int R) {
        int r = tid >> 1, half = tid & 1;
        if (r < R) {
            const ushort* src = tbg + (size_t)r * 256 + half * 16;
            uint4 p0 = *(const uint4*)src, p1 = *(const uint4*)(src + 8);
            const ushort* u0 = (const ushort*)&p0;
            const ushort* u1 = (const ushort*)&p1;
#pragma unroll
            for (int ii = 0; ii < 8; ++ii) {
                vtbl[(half * 16 + ii) * 136 + r] = u0[ii];
                vtbl[(half * 16 + 8 + ii) * 136 + r] = u1[ii];
            }
        }
        int span = 128 - R;
        for (int e = tid; e < 32 * span; e += 256) {
            int d = e / span, rr = e - d * span;
            vtbl[d * 136 + R + rr] = 0;
        }
    };
    auto stageVt = [&]() {
        int j = tid >> 2, d0 = (tid & 3) * 8;
        uint4 pk = *(const uint4*)(vb + base + tid * 8);
        const ushort* u = (const ushort*)&pk;
#pragma unroll
        for (int ii = 0; ii < 8; ++ii) v_t[(d0 + ii) * 72 + j] = u[ii];
    };

    auto tgemm = [&](const ushort* a_s, int NT, int maxc) {
        short8 af = *(const short8*)&a_s[(w * 16 + l4) * 40 + quad * 8];
        for (int tt = 0; tt < NT; ++tt) {
            short8 bf = *(const short8*)&tbl[(tt * 16 + l4) * 40 + quad * 8];
            f32x4 a = {0.f, 0.f, 0.f, 0.f};
            a = __builtin_amdgcn_mfma_f32_16x16x32_bf16(af, bf, a, 0, 0, 0);
            int col = tt * 16 + l4;
            int rb = w * 16 + quad * 4;
            if (col < maxc) {
                dbuf[(rb + 0) * DBS + col] = a[0];
                dbuf[(rb + 1) * DBS + col] = a[1];
                dbuf[(rb + 2) * DBS + col] = a[2];
                dbuf[(rb + 3) * DBS + col] = a[3];
            }
        }
    };

    stageTbl(kxt + h * 32, 120, 128);
    __syncthreads();

    // ---- precompute gather/scatter indices once (packed t0|t1<<8|t2<<16) ----
    int idxX[4][4], idxR[4][4];   // [tt][reg]
    {
        float ci[4][6];
#pragma unroll
        for (int reg = 0; reg < 4; ++reg) {
            int i = w * 16 + quad * 4 + reg;
#pragma unroll
            for (int c = 0; c < 6; ++c) ci[reg][c] = cwf[i * 6 + c];
        }
#pragma unroll
        for (int tt = 0; tt < 4; ++tt) {
            int j = tt * 16 + l4;
            float cj0 = cwf[j * 6 + 0], cj1 = cwf[j * 6 + 1], cj2 = cwf[j * 6 + 2];
            float cj3 = cwf[j * 6 + 3], cj4 = cwf[j * 6 + 4], cj5 = cwf[j * 6 + 5];
#pragma unroll
            for (int reg = 0; reg < 4; ++reg) {
                int x0 = min(max((int)floorf(ci[reg][0] - cj0) + 20, 0), 39);
                int x1 = min(max((int)floorf(ci[reg][1] - cj1) + 20, 0), 39);
                int x2 = min(max((int)floorf(ci[reg][2] - cj2) + 20, 0), 39);
                idxX[tt][reg] = x0 | (x1 << 8) | (x2 << 16);
                int r0 = min(max((int)floorf(ci[reg][3] - cj3) + 16, 0), 31);
                int r1 = min(max((int)floorf(ci[reg][4] - cj4) + 16, 0), 31);
                int r2 = min(max((int)floorf(ci[reg][5] - cj5) + 16, 0), 31);
                idxR[tt][reg] = r0 | (r1 << 8) | (r2 << 16);
            }
        }
    }

    float lg[4][4];   // [tt][reg]: row i = w*16+quad*4+reg, col j = tt*16+l4

    auto gather = [&](const int (*idx)[4], int T, bool useJ) {
#pragma unroll
        for (int tt = 0; tt < 4; ++tt) {
#pragma unroll
            for (int reg = 0; reg < 4; ++reg) {
                int p = idx[tt][reg];
                int b = (useJ ? (tt * 16 + l4) : (w * 16 + quad * 4 + reg)) * DBS;
                lg[tt][reg] += dbuf[b + (p & 255)] + dbuf[b + T + ((p >> 8) & 255)]
                             + dbuf[b + 2 * T + (p >> 16)];
            }
        }
    };
    auto scatter = [&](const int (*idx)[4], int T) {
#pragma unroll
        for (int reg = 0; reg < 4; ++reg) {
            float* bi = &dbuf[(w * 16 + quad * 4 + reg) * DBS];
#pragma unroll
            for (int tt = 0; tt < 4; ++tt) {
                int p = idx[tt][reg];
                float a = lg[tt][reg];
                atomicAdd(bi + (p & 255), a);
                atomicAdd(bi + T + ((p >> 8) & 255), a);
                atomicAdd(bi + 2 * T + (p >> 16), a);
            }
        }
    };
    auto zeroBins = [&]() {
        float4 z = {0.f, 0.f, 0.f, 0.f};
        for (int e = tid * 4; e < 64 * DBS; e += 1024) *(float4*)&dbuf[e] = z;
    };

    // ---- QK logits + dk_xyz ----
    {
        short8 aq = *(const short8*)&q_s[(w * 16 + l4) * 40 + quad * 8];
#pragma unroll
        for (int tt = 0; tt < 4; ++tt) {
            short8 bk = *(const short8*)&k_s[(tt * 16 + l4) * 40 + quad * 8];
            f32x4 r = {0.f, 0.f, 0.f, 0.f};
            r = __builtin_amdgcn_mfma_f32_16x16x32_bf16(aq, bk, r, 0, 0, 0);
            lg[tt][0] = r[0]; lg[tt][1] = r[1]; lg[tt][2] = r[2]; lg[tt][3] = r[3];
        }
    }
    tgemm(k_s, 8, 120);                  // dk_xyz
    __syncthreads();
    gather(idxX, 40, true);              // bias_k xyz
    stageTbl(krt + h * 32, 96, 96);
    __syncthreads();
    tgemm(k_s, 6, 96);                   // dk_rgb
    __syncthreads();
    gather(idxR, 32, true);              // bias_k rgb
    stageTbl(qxt + h * 32, 120, 128);
    __syncthreads();
    tgemm(q_s, 8, 120);                  // dq_xyz
    __syncthreads();
    gather(idxX, 40, false);             // bias_q xyz
    stageTbl(qrt + h * 32, 96, 96);
    __syncthreads();
    tgemm(q_s, 6, 96);                   // dq_rgb
    __syncthreads();
    gather(idxR, 32, false);             // bias_q rgb
    stageVtbl(vxt + h * 32, 120);        // tbl + cw regions dead now
    stageVt();                           // k_s tail dead now
    __syncthreads();

    // ---- softmax ----
#pragma unroll
    for (int reg = 0; reg < 4; ++reg) {
        float m = fmaxf(fmaxf(lg[0][reg], lg[1][reg]), fmaxf(lg[2][reg], lg[3][reg]));
        m = fmaxf(m, __shfl_xor(m, 1));
        m = fmaxf(m, __shfl_xor(m, 2));
        m = fmaxf(m, __shfl_xor(m, 4));
        m = fmaxf(m, __shfl_xor(m, 8));
        float s = 0.f;
#pragma unroll
        for (int tt = 0; tt < 4; ++tt) { lg[tt][reg] = __expf(lg[tt][reg] - m); s += lg[tt][reg]; }
        s += __shfl_xor(s, 1); s += __shfl_xor(s, 2);
        s += __shfl_xor(s, 4); s += __shfl_xor(s, 8);
        float inv = 1.f / s;
#pragma unroll
        for (int tt = 0; tt < 4; ++tt) lg[tt][reg] *= inv;
    }
#pragma unroll
    for (int tt = 0; tt < 4; ++tt)
#pragma unroll
        for (int reg = 0; reg < 4; ++reg)
            attn_s[(w * 16 + quad * 4 + reg) * 72 + tt * 16 + l4] = f2bf(lg[tt][reg]);
    zeroBins();
    __syncthreads();

    // ---- scatter xyz bins + AV ----
    scatter(idxX, 40);
    f32x4 acc0 = {0.f, 0.f, 0.f, 0.f}, acc1 = {0.f, 0.f, 0.f, 0.f};
#pragma unroll
    for (int s = 0; s < 2; ++s) {
        short8 af = *(const short8*)&attn_s[(w * 16 + l4) * 72 + s * 32 + quad * 8];
        short8 b0 = *(const short8*)&v_t[l4 * 72 + s * 32 + quad * 8];
        short8 b1 = *(const short8*)&v_t[(16 + l4) * 72 + s * 32 + quad * 8];
        acc0 = __builtin_amdgcn_mfma_f32_16x16x32_bf16(af, b0, acc0, 0, 0, 0);
        acc1 = __builtin_amdgcn_mfma_f32_16x16x32_bf16(af, b1, acc1, 0, 0, 0);
    }
    __syncthreads();

    auto atgemm = [&](int Rlim) {
#pragma unroll
        for (int s = 0; s < 4; ++s) {
            int koff = s * 32 + quad * 8;
            short8 af = {0, 0, 0, 0, 0, 0, 0, 0};
            if (koff < Rlim) {
                const float* ap = &dbuf[(w * 16 + l4) * DBS + koff];
#pragma unroll
                for (int ii = 0; ii < 8; ++ii) af[ii] = (short)f2bf(ap[ii]);
            }
            short8 b0 = *(const short8*)&vtbl[l4 * 136 + koff];
            short8 b1 = *(const short8*)&vtbl[(16 + l4) * 136 + koff];
            acc0 = __builtin_amdgcn_mfma_f32_16x16x32_bf16(af, b0, acc0, 0, 0, 0);
            acc1 = __builtin_amdgcn_mfma_f32_16x16x32_bf16(af, b1, acc1, 0, 0, 0);
        }
    };
    atgemm(120);                         // value-bias xyz
    __syncthreads();
    zeroBins();
    stageVtbl(vrt + h * 32, 96);
    __syncthreads();
    scatter(idxR, 32);
    __syncthreads();
    atgemm(96);                          // value-bias rgb

    // ---- epilogue: bf16 ao[i][h*32+d] ----
    {
        ushort* op = aout + (size_t)(n * 64 + w * 16 + quad * 4) * 256 + h * 32;
#pragma unroll
        for (int reg = 0; reg < 4; ++reg) {
            op[reg * 256 + l4] = f2bf(acc0[reg]);
            op[reg * 256 + 16 + l4] = f2bf(acc1[reg]);
        }
    }
}

// ---------------------------------------------------------------------------
// Proj GEMM (bf16 MFMA): out = ao @ proj_w^T + proj_b (fp32 out)
// ---------------------------------------------------------------------------
__global__ __launch_bounds__(256) void k_proj(
    const ushort* __restrict__ A, const ushort* __restrict__ B,
    const float* __restrict__ bias, float* __restrict__ out)
{
    __shared__ __align__(16) ushort a_s[128 * 72];
    __shared__ __align__(16) ushort b_s[64 * 72];
    const int tid = threadIdx.x;
    const int m0 = blockIdx.y * 128;
    const int n0 = blockIdx.x * 64;
    const int w = tid >> 6, wm = w >> 1, wn = w & 1;
    const int l4 = tid & 15, quad = (tid >> 4) & 3;
    f32x4 acc[4][2];
#pragma unroll
    for (int mt = 0; mt < 4; ++mt)
#pragma unroll
        for (int nt = 0; nt < 2; ++nt) acc[mt][nt] = (f32x4){0.f, 0.f, 0.f, 0.f};

    for (int k0 = 0; k0 < 256; k0 += 64) {
#pragma unroll
        for (int l = 0; l < 4; ++l) {
            int e = tid + l * 256;
            int row = e >> 3, kq = e & 7;
            *(uint4*)&a_s[row * 72 + kq * 8] =
                *(const uint4*)(A + (size_t)(m0 + row) * 256 + k0 + kq * 8);
        }
#pragma unroll
        for (int l = 0; l < 2; ++l) {
            int e = tid + l * 256;
            int row = e >> 3, kq = e & 7;
            *(uint4*)&b_s[row * 72 + kq * 8] =
                *(const uint4*)(B + (size_t)(n0 + row) * 256 + k0 + kq * 8);
        }
        __syncthreads();
#pragma unroll
        for (int kh = 0; kh < 2; ++kh) {
            short8 bf0 = *(const short8*)&b_s[(wn * 32 + l4) * 72 + kh * 32 + quad * 8];
            short8 bf1 = *(const short8*)&b_s[(wn * 32 + 16 + l4) * 72 + kh * 32 + quad * 8];
#pragma unroll
            for (int mt = 0; mt < 4; ++mt) {
                short8 af = *(const short8*)&a_s[(wm * 64 + mt * 16 + l4) * 72 + kh * 32 + quad * 8];
                acc[mt][0] = __builtin_amdgcn_mfma_f32_16x16x32_bf16(af, bf0, acc[mt][0], 0, 0, 0);
                acc[mt][1] = __builtin_amdgcn_mfma_f32_16x16x32_bf16(af, bf1, acc[mt][1], 0, 0, 0);
            }
        }
        __syncthreads();
    }
#pragma unroll
    for (int nt = 0; nt < 2; ++nt) {
        int c = n0 + wn * 32 + nt * 16 + l4;
        float bv = bias[c];
#pragma unroll
        for (int mt = 0; mt < 4; ++mt) {
            int mbase = m0 + wm * 64 + mt * 16 + quad * 4;
#pragma unroll
            for (int reg = 0; reg < 4; ++reg)
                out[(size_t)(mbase + reg) * 256 + c] = acc[mt][nt][reg] + bv;
        }
    }
}

extern "C" void kernel_launch(void* const* d_in, const int* in_sizes, int n_in,
                              void* d_out, int out_size, void* d_ws, size_t ws_size,
                              hipStream_t stream)
{
    const float* feats = (const float*)d_in[0];
    const float* nco   = (const float*)d_in[1];
    const float* qkvw  = (const float*)d_in[2];
    const float* qkvb  = (const float*)d_in[3];
    const float* qxt   = (const float*)d_in[4];
    const float* kxt   = (const float*)d_in[5];
    const float* vxt   = (const float*)d_in[6];
    const float* qrt   = (const float*)d_in[7];
    const float* krt   = (const float*)d_in[8];
    const float* vrt   = (const float*)d_in[9];
    const float* pw    = (const float*)d_in[10];
    const float* pb    = (const float*)d_in[11];
    float* out = (float*)d_out;

    ushort* qb  = (ushort*)d_ws;                       // [128][8][64][32]
    ushort* kb  = qb + (size_t)2097152;
    ushort* vb  = kb + (size_t)2097152;
    ushort* aob = vb + (size_t)2097152;                // [8192][256] bf16
    ushort* cst = aob + (size_t)2097152;               // bf16 cast region
    ushort* featsB = cst;                              // 2,097,152 el
    ushort* qkvwB  = cst + (size_t)2097152;            //   196,608 el
    ushort* projwB = cst + (size_t)2293760;            //    65,536 el
    ushort* qxtB   = cst + (size_t)2359296;            //    30,720 el
    ushort* kxtB   = cst + (size_t)2390016;
    ushort* vxtB   = cst + (size_t)2420736;
    ushort* qrtB   = cst + (size_t)2451456;            //    24,576 el
    ushort* krtB   = cst + (size_t)2476032;
    ushort* vrtB   = cst + (size_t)2500608;            // end 2,525,184 el

    k_cast<<<dim3(2466), 256, 0, stream>>>(feats, qkvw, pw, qxt, kxt, vxt, qrt, krt, vrt, cst);
    k_qkv<<<dim3(12, 64), 256, 0, stream>>>(featsB, qkvwB, qkvb, qb, kb, vb);
    k_attn<<<dim3(1024), 256, 0, stream>>>(qb, kb, vb, nco, qxtB, kxtB, vxtB, qrtB, krtB, vrtB, aob);
    k_proj<<<dim3(4, 64), 256, 0, stream>>>(aob, projwB, pb, out);
}

// Round 5
// 306.688 us; speedup vs baseline: 1.1021x; 1.1021x over previous
//
#include <hip/hip_runtime.h>

// DIM=256 H=8 HD=32 W=64 N=8192 nw=128
// xyz: T=40, off=20, hi=39, R=120 (pad 128) ; rgb: T=32, off=16, hi=31, R=96
// table element ((c*T+t)*8+h)*32+d == r*256 + h*32 + d, r=c*T+t
// table sizes: xyz 120*256 = 30,720 el = 7,680 float4 ; rgb 96*256 = 24,576 el = 6,144 float4

typedef __attribute__((ext_vector_type(8))) short short8;
typedef __attribute__((ext_vector_type(4))) float f32x4;

__device__ __forceinline__ unsigned short f2bf(float f) {
    union { float f; unsigned int u; } v; v.f = f;
    unsigned int r = v.u + 0x7FFFu + ((v.u >> 16) & 1u);
    return (unsigned short)(r >> 16);
}

// ---------------------------------------------------------------------------
// Cast prepass: fp32 -> bf16 for feats, qkv_w, proj_w, 6 tables.
// ---------------------------------------------------------------------------
__global__ __launch_bounds__(256) void k_cast(
    const float* __restrict__ s0, const float* __restrict__ s1,
    const float* __restrict__ s2, const float* __restrict__ s3,
    const float* __restrict__ s4, const float* __restrict__ s5,
    const float* __restrict__ s6, const float* __restrict__ s7,
    const float* __restrict__ s8, ushort* __restrict__ dst)
{
    unsigned g = blockIdx.x * 256 + threadIdx.x;   // float4 index, < 631296
    const float* src;
    unsigned base;
    if      (g < 524288u) { src = s0; base = 0; }
    else if (g < 573440u) { src = s1; base = 524288u; }
    else if (g < 589824u) { src = s2; base = 573440u; }
    else if (g < 597504u) { src = s3; base = 589824u; }
    else if (g < 605184u) { src = s4; base = 597504u; }
    else if (g < 612864u) { src = s5; base = 605184u; }
    else if (g < 619008u) { src = s6; base = 612864u; }
    else if (g < 625152u) { src = s7; base = 619008u; }
    else                  { src = s8; base = 625152u; }
    float4 v = *(const float4*)(src + (size_t)(g - base) * 4);
    ushort4 o;
    o.x = f2bf(v.x); o.y = f2bf(v.y); o.z = f2bf(v.z); o.w = f2bf(v.w);
    *(ushort4*)(dst + (size_t)g * 4) = o;
}

// ---------------------------------------------------------------------------
// QKV GEMM (bf16 MFMA): qkv = feats @ qkv_w^T + b -> q/k/v bf16 [nw][H][W][HD]
// ---------------------------------------------------------------------------
__global__ __launch_bounds__(256) void k_qkv(
    const ushort* __restrict__ A, const ushort* __restrict__ B,
    const float* __restrict__ bias,
    ushort* __restrict__ qb, ushort* __restrict__ kb, ushort* __restrict__ vb)
{
    __shared__ __align__(16) ushort a_s[128 * 72];
    __shared__ __align__(16) ushort b_s[64 * 72];
    const int tid = threadIdx.x;
    const int m0 = blockIdx.y * 128;
    const int n0 = blockIdx.x * 64;
    const int w = tid >> 6, wm = w >> 1, wn = w & 1;
    const int l4 = tid & 15, quad = (tid >> 4) & 3;
    f32x4 acc[4][2];
#pragma unroll
    for (int mt = 0; mt < 4; ++mt)
#pragma unroll
        for (int nt = 0; nt < 2; ++nt) acc[mt][nt] = (f32x4){0.f, 0.f, 0.f, 0.f};

    for (int k0 = 0; k0 < 256; k0 += 64) {
#pragma unroll
        for (int l = 0; l < 4; ++l) {
            int e = tid + l * 256;
            int row = e >> 3, kq = e & 7;
            *(uint4*)&a_s[row * 72 + kq * 8] =
                *(const uint4*)(A + (size_t)(m0 + row) * 256 + k0 + kq * 8);
        }
#pragma unroll
        for (int l = 0; l < 2; ++l) {
            int e = tid + l * 256;
            int row = e >> 3, kq = e & 7;
            *(uint4*)&b_s[row * 72 + kq * 8] =
                *(const uint4*)(B + (size_t)(n0 + row) * 256 + k0 + kq * 8);
        }
        __syncthreads();
#pragma unroll
        for (int kh = 0; kh < 2; ++kh) {
            short8 bf0 = *(const short8*)&b_s[(wn * 32 + l4) * 72 + kh * 32 + quad * 8];
            short8 bf1 = *(const short8*)&b_s[(wn * 32 + 16 + l4) * 72 + kh * 32 + quad * 8];
#pragma unroll
            for (int mt = 0; mt < 4; ++mt) {
                short8 af = *(const short8*)&a_s[(wm * 64 + mt * 16 + l4) * 72 + kh * 32 + quad * 8];
                acc[mt][0] = __builtin_amdgcn_mfma_f32_16x16x32_bf16(af, bf0, acc[mt][0], 0, 0, 0);
                acc[mt][1] = __builtin_amdgcn_mfma_f32_16x16x32_bf16(af, bf1, acc[mt][1], 0, 0, 0);
            }
        }
        __syncthreads();
    }
#pragma unroll
    for (int nt = 0; nt < 2; ++nt) {
        int c = n0 + wn * 32 + nt * 16 + l4;
        float bv = bias[c];
        int s = c >> 8, rem = c & 255, h = rem >> 5, d = rem & 31;
        ushort* dst = (s == 0) ? qb : ((s == 1) ? kb : vb);
        float mul = (s == 0) ? 0.17677669529663687f : 1.0f;
#pragma unroll
        for (int mt = 0; mt < 4; ++mt) {
            int mbase = m0 + wm * 64 + mt * 16 + quad * 4;
#pragma unroll
            for (int reg = 0; reg < 4; ++reg) {
                int m = mbase + reg;
                int nw = m >> 6, ii = m & 63;
                dst[((size_t)((nw * 8 + h) * 64 + ii)) * 32 + d] = f2bf((acc[mt][nt][reg] + bv) * mul);
            }
        }
    }
}

// ---------------------------------------------------------------------------
// MFMA attention per (window, head). 4 waves; wave w owns rows w*16..w*16+15.
// A/B frag: [outer=lane&15][k=quad*8+j] ; C/D: col=lane&15, row=quad*4+reg.
// LDS: dbuf fp32 64x122 (31,232 B) + ushort union U (22,528 B) = 53,760 B
// -> 3 blocks/CU. idxX/idxR MUST stay register-resident: no address-taking,
// constant indices only (round-4 spill post-mortem: pointer params -> scratch).
// ---------------------------------------------------------------------------
#define DBS 122

__global__ __launch_bounds__(256, 3) void k_attn(
    const ushort* __restrict__ qb, const ushort* __restrict__ kb, const ushort* __restrict__ vb,
    const float* __restrict__ nco,
    const ushort* __restrict__ qxt, const ushort* __restrict__ kxt, const ushort* __restrict__ vxt,
    const ushort* __restrict__ qrt, const ushort* __restrict__ krt, const ushort* __restrict__ vrt,
    ushort* __restrict__ aout)
{
    __shared__ __align__(16) float dbuf[64 * DBS];
    __shared__ __align__(16) ushort U[11264];
    // Phase A overlays:
    ushort* q_s  = U;              // [64][40]
    ushort* k_s  = U + 2560;       // [64][40]
    ushort* tbl  = U + 5120;       // [128][40]
    float*  cwf  = (float*)(U + 10240);  // [64][6], dead after idx precompute
    // Phase B overlays:
    ushort* attn_s = U;            // [64][72]
    ushort* v_t    = U + 4608;     // [32][72]
    ushort* vtbl   = U + 6912;     // [32][136]

    const int tid = threadIdx.x;
    const int n = blockIdx.x >> 3;
    const int h = blockIdx.x & 7;
    const int w = tid >> 6;
    const int l4 = tid & 15;
    const int quad = (tid >> 4) & 3;

    const size_t base = (size_t)((n * 8 + h) * 64) * 32;

    // ---- stage q, k, coords ----
    {
        int row = tid >> 2, part = tid & 3;
        *(uint4*)&q_s[row * 40 + part * 8] = *(const uint4*)(qb + base + tid * 8);
        *(uint4*)&k_s[row * 40 + part * 8] = *(const uint4*)(kb + base + tid * 8);
    }
    if (tid < 64) {
        const float* cp = nco + (size_t)(n * 64 + tid) * 6;
        cwf[tid * 6 + 0] = cp[0] * 4.f; cwf[tid * 6 + 1] = cp[1] * 4.f;
        cwf[tid * 6 + 2] = cp[2] * 4.f; cwf[tid * 6 + 3] = cp[3] * 8.f;
        cwf[tid * 6 + 4] = cp[4] * 8.f; cwf[tid * 6 + 5] = cp[5] * 8.f;
    }

    auto stageTbl = [&](const ushort* tbg, int R, int Rpad) {
        int r = tid >> 1, half = tid & 1;
        if (r < R) {
            const ushort* src = tbg + (size_t)r * 256 + half * 16;
            ushort* dp = &tbl[r * 40 + half * 16];
            *(uint4*)dp = *(const uint4*)src;
            *(uint4*)(dp + 8) = *(const uint4*)(src + 8);
        }
        for (int e = tid; e < (Rpad - R) * 40; e += 256) tbl[R * 40 + e] = 0;
    };
    auto stageVtbl = [&](const ushort* tbg, int R) {
        int r = tid >> 1, half = tid & 1;
        if (r < R) {
            const ushort* src = tbg + (size_t)r * 256 + half * 16;
            uint4 p0 = *(const uint4*)src, p1 = *(const uint4*)(src + 8);
            const ushort* u0 = (const ushort*)&p0;
            const ushort* u1 = (const ushort*)&p1;
#pragma unroll
            for (int ii = 0; ii < 8; ++ii) {
                vtbl[(half * 16 + ii) * 136 + r] = u0[ii];
                vtbl[(half * 16 + 8 + ii) * 136 + r] = u1[ii];
            }
        }
        int span = 128 - R;
        for (int e = tid; e < 32 * span; e += 256) {
            int d = e / span, rr = e - d * span;
            vtbl[d * 136 + R + rr] = 0;
        }
    };
    auto stageVt = [&]() {
        int j = tid >> 2, d0 = (tid & 3) * 8;
        uint4 pk = *(const uint4*)(vb + base + tid * 8);
        const ushort* u = (const ushort*)&pk;
#pragma unroll
        for (int ii = 0; ii < 8; ++ii) v_t[(d0 + ii) * 72 + j] = u[ii];
    };

    auto tgemm = [&](const ushort* a_s, int NT, int maxc) {
        short8 af = *(const short8*)&a_s[(w * 16 + l4) * 40 + quad * 8];
        for (int tt = 0; tt < NT; ++tt) {
            short8 bf = *(const short8*)&tbl[(tt * 16 + l4) * 40 + quad * 8];
            f32x4 a = {0.f, 0.f, 0.f, 0.f};
            a = __builtin_amdgcn_mfma_f32_16x16x32_bf16(af, bf, a, 0, 0, 0);
            int col = tt * 16 + l4;
            int rb = w * 16 + quad * 4;
            if (col < maxc) {
                dbuf[(rb + 0) * DBS + col] = a[0];
                dbuf[(rb + 1) * DBS + col] = a[1];
                dbuf[(rb + 2) * DBS + col] = a[2];
                dbuf[(rb + 3) * DBS + col] = a[3];
            }
        }
    };

    stageTbl(kxt + h * 32, 120, 128);
    __syncthreads();

    // ---- precompute gather/scatter indices once (packed t0|t1<<8|t2<<16) ----
    // Kept strictly register-resident: constant-indexed, never address-taken.
    int idxX[4][4], idxR[4][4];   // [tt][reg]
    {
#pragma unroll
        for (int tt = 0; tt < 4; ++tt) {
            int j = tt * 16 + l4;
            float cj0 = cwf[j * 6 + 0], cj1 = cwf[j * 6 + 1], cj2 = cwf[j * 6 + 2];
            float cj3 = cwf[j * 6 + 3], cj4 = cwf[j * 6 + 4], cj5 = cwf[j * 6 + 5];
#pragma unroll
            for (int reg = 0; reg < 4; ++reg) {
                int i = w * 16 + quad * 4 + reg;
                int x0 = min(max((int)floorf(cwf[i * 6 + 0] - cj0) + 20, 0), 39);
                int x1 = min(max((int)floorf(cwf[i * 6 + 1] - cj1) + 20, 0), 39);
                int x2 = min(max((int)floorf(cwf[i * 6 + 2] - cj2) + 20, 0), 39);
                idxX[tt][reg] = x0 | (x1 << 8) | (x2 << 16);
                int r0 = min(max((int)floorf(cwf[i * 6 + 3] - cj3) + 16, 0), 31);
                int r1 = min(max((int)floorf(cwf[i * 6 + 4] - cj4) + 16, 0), 31);
                int r2 = min(max((int)floorf(cwf[i * 6 + 5] - cj5) + 16, 0), 31);
                idxR[tt][reg] = r0 | (r1 << 8) | (r2 << 16);
            }
        }
    }

    float lg[4][4];   // [tt][reg]: row i = w*16+quad*4+reg, col j = tt*16+l4

    auto gatherX = [&](bool useJ) {
#pragma unroll
        for (int tt = 0; tt < 4; ++tt) {
#pragma unroll
            for (int reg = 0; reg < 4; ++reg) {
                int p = idxX[tt][reg];
                int b = (useJ ? (tt * 16 + l4) : (w * 16 + quad * 4 + reg)) * DBS;
                lg[tt][reg] += dbuf[b + (p & 255)] + dbuf[b + 40 + ((p >> 8) & 255)]
                             + dbuf[b + 80 + (p >> 16)];
            }
        }
    };
    auto gatherR = [&](bool useJ) {
#pragma unroll
        for (int tt = 0; tt < 4; ++tt) {
#pragma unroll
            for (int reg = 0; reg < 4; ++reg) {
                int p = idxR[tt][reg];
                int b = (useJ ? (tt * 16 + l4) : (w * 16 + quad * 4 + reg)) * DBS;
                lg[tt][reg] += dbuf[b + (p & 255)] + dbuf[b + 32 + ((p >> 8) & 255)]
                             + dbuf[b + 64 + (p >> 16)];
            }
        }
    };
    auto scatterX = [&]() {
#pragma unroll
        for (int reg = 0; reg < 4; ++reg) {
            float* bi = &dbuf[(w * 16 + quad * 4 + reg) * DBS];
#pragma unroll
            for (int tt = 0; tt < 4; ++tt) {
                int p = idxX[tt][reg];
                float a = lg[tt][reg];
                atomicAdd(bi + (p & 255), a);
                atomicAdd(bi + 40 + ((p >> 8) & 255), a);
                atomicAdd(bi + 80 + (p >> 16), a);
            }
        }
    };
    auto scatterR = [&]() {
#pragma unroll
        for (int reg = 0; reg < 4; ++reg) {
            float* bi = &dbuf[(w * 16 + quad * 4 + reg) * DBS];
#pragma unroll
            for (int tt = 0; tt < 4; ++tt) {
                int p = idxR[tt][reg];
                float a = lg[tt][reg];
                atomicAdd(bi + (p & 255), a);
                atomicAdd(bi + 32 + ((p >> 8) & 255), a);
                atomicAdd(bi + 64 + (p >> 16), a);
            }
        }
    };
    auto zeroBins = [&]() {
        float4 z = {0.f, 0.f, 0.f, 0.f};
        for (int e = tid * 4; e < 64 * DBS; e += 1024) *(float4*)&dbuf[e] = z;
    };

    // ---- QK logits + dk_xyz ----
    {
        short8 aq = *(const short8*)&q_s[(w * 16 + l4) * 40 + quad * 8];
#pragma unroll
        for (int tt = 0; tt < 4; ++tt) {
            short8 bk = *(const short8*)&k_s[(tt * 16 + l4) * 40 + quad * 8];
            f32x4 r = {0.f, 0.f, 0.f, 0.f};
            r = __builtin_amdgcn_mfma_f32_16x16x32_bf16(aq, bk, r, 0, 0, 0);
            lg[tt][0] = r[0]; lg[tt][1] = r[1]; lg[tt][2] = r[2]; lg[tt][3] = r[3];
        }
    }
    tgemm(k_s, 8, 120);                  // dk_xyz
    __syncthreads();
    gatherX(true);                       // bias_k xyz
    stageTbl(krt + h * 32, 96, 96);
    __syncthreads();
    tgemm(k_s, 6, 96);                   // dk_rgb
    __syncthreads();
    gatherR(true);                       // bias_k rgb
    stageTbl(qxt + h * 32, 120, 128);
    __syncthreads();
    tgemm(q_s, 8, 120);                  // dq_xyz
    __syncthreads();
    gatherX(false);                      // bias_q xyz
    stageTbl(qrt + h * 32, 96, 96);
    __syncthreads();
    tgemm(q_s, 6, 96);                   // dq_rgb
    __syncthreads();
    gatherR(false);                      // bias_q rgb
    stageVtbl(vxt + h * 32, 120);        // tbl + cw regions dead now
    stageVt();                           // k_s tail dead now
    __syncthreads();

    // ---- softmax ----
#pragma unroll
    for (int reg = 0; reg < 4; ++reg) {
        float m = fmaxf(fmaxf(lg[0][reg], lg[1][reg]), fmaxf(lg[2][reg], lg[3][reg]));
        m = fmaxf(m, __shfl_xor(m, 1));
        m = fmaxf(m, __shfl_xor(m, 2));
        m = fmaxf(m, __shfl_xor(m, 4));
        m = fmaxf(m, __shfl_xor(m, 8));
        float s = 0.f;
#pragma unroll
        for (int tt = 0; tt < 4; ++tt) { lg[tt][reg] = __expf(lg[tt][reg] - m); s += lg[tt][reg]; }
        s += __shfl_xor(s, 1); s += __shfl_xor(s, 2);
        s += __shfl_xor(s, 4); s += __shfl_xor(s, 8);
        float inv = 1.f / s;
#pragma unroll
        for (int tt = 0; tt < 4; ++tt) lg[tt][reg] *= inv;
    }
#pragma unroll
    for (int tt = 0; tt < 4; ++tt)
#pragma unroll
        for (int reg = 0; reg < 4; ++reg)
            attn_s[(w * 16 + quad * 4 + reg) * 72 + tt * 16 + l4] = f2bf(lg[tt][reg]);
    zeroBins();
    __syncthreads();

    // ---- scatter xyz bins + AV ----
    scatterX();
    f32x4 acc0 = {0.f, 0.f, 0.f, 0.f}, acc1 = {0.f, 0.f, 0.f, 0.f};
#pragma unroll
    for (int s = 0; s < 2; ++s) {
        short8 af = *(const short8*)&attn_s[(w * 16 + l4) * 72 + s * 32 + quad * 8];
        short8 b0 = *(const short8*)&v_t[l4 * 72 + s * 32 + quad * 8];
        short8 b1 = *(const short8*)&v_t[(16 + l4) * 72 + s * 32 + quad * 8];
        acc0 = __builtin_amdgcn_mfma_f32_16x16x32_bf16(af, b0, acc0, 0, 0, 0);
        acc1 = __builtin_amdgcn_mfma_f32_16x16x32_bf16(af, b1, acc1, 0, 0, 0);
    }
    __syncthreads();

    auto atgemm = [&](int Rlim) {
#pragma unroll
        for (int s = 0; s < 4; ++s) {
            int koff = s * 32 + quad * 8;
            short8 af = {0, 0, 0, 0, 0, 0, 0, 0};
            if (koff < Rlim) {
                const float* ap = &dbuf[(w * 16 + l4) * DBS + koff];
#pragma unroll
                for (int ii = 0; ii < 8; ++ii) af[ii] = (short)f2bf(ap[ii]);
            }
            short8 b0 = *(const short8*)&vtbl[l4 * 136 + koff];
            short8 b1 = *(const short8*)&vtbl[(16 + l4) * 136 + koff];
            acc0 = __builtin_amdgcn_mfma_f32_16x16x32_bf16(af, b0, acc0, 0, 0, 0);
            acc1 = __builtin_amdgcn_mfma_f32_16x16x32_bf16(af, b1, acc1, 0, 0, 0);
        }
    };
    atgemm(120);                         // value-bias xyz
    __syncthreads();
    zeroBins();
    stageVtbl(vrt + h * 32, 96);
    __syncthreads();
    scatterR();
    __syncthreads();
    atgemm(96);                          // value-bias rgb

    // ---- epilogue: bf16 ao[i][h*32+d] ----
    {
        ushort* op = aout + (size_t)(n * 64 + w * 16 + quad * 4) * 256 + h * 32;
#pragma unroll
        for (int reg = 0; reg < 4; ++reg) {
            op[reg * 256 + l4] = f2bf(acc0[reg]);
            op[reg * 256 + 16 + l4] = f2bf(acc1[reg]);
        }
    }
}

// ---------------------------------------------------------------------------
// Proj GEMM (bf16 MFMA): out = ao @ proj_w^T + proj_b (fp32 out)
// ---------------------------------------------------------------------------
__global__ __launch_bounds__(256) void k_proj(
    const ushort* __restrict__ A, const ushort* __restrict__ B,
    const float* __restrict__ bias, float* __restrict__ out)
{
    __shared__ __align__(16) ushort a_s[128 * 72];
    __shared__ __align__(16) ushort b_s[64 * 72];
    const int tid = threadIdx.x;
    const int m0 = blockIdx.y * 128;
    const int n0 = blockIdx.x * 64;
    const int w = tid >> 6, wm = w >> 1, wn = w & 1;
    const int l4 = tid & 15, quad = (tid >> 4) & 3;
    f32x4 acc[4][2];
#pragma unroll
    for (int mt = 0; mt < 4; ++mt)
#pragma unroll
        for (int nt = 0; nt < 2; ++nt) acc[mt][nt] = (f32x4){0.f, 0.f, 0.f, 0.f};

    for (int k0 = 0; k0 < 256; k0 += 64) {
#pragma unroll
        for (int l = 0; l < 4; ++l) {
            int e = tid + l * 256;
            int row = e >> 3, kq = e & 7;
            *(uint4*)&a_s[row * 72 + kq * 8] =
                *(const uint4*)(A + (size_t)(m0 + row) * 256 + k0 + kq * 8);
        }
#pragma unroll
        for (int l = 0; l < 2; ++l) {
            int e = tid + l * 256;
            int row = e >> 3, kq = e & 7;
            *(uint4*)&b_s[row * 72 + kq * 8] =
                *(const uint4*)(B + (size_t)(n0 + row) * 256 + k0 + kq * 8);
        }
        __syncthreads();
#pragma unroll
        for (int kh = 0; kh < 2; ++kh) {
            short8 bf0 = *(const short8*)&b_s[(wn * 32 + l4) * 72 + kh * 32 + quad * 8];
            short8 bf1 = *(const short8*)&b_s[(wn * 32 + 16 + l4) * 72 + kh * 32 + quad * 8];
#pragma unroll
            for (int mt = 0; mt < 4; ++mt) {
                short8 af = *(const short8*)&a_s[(wm * 64 + mt * 16 + l4) * 72 + kh * 32 + quad * 8];
                acc[mt][0] = __builtin_amdgcn_mfma_f32_16x16x32_bf16(af, bf0, acc[mt][0], 0, 0, 0);
                acc[mt][1] = __builtin_amdgcn_mfma_f32_16x16x32_bf16(af, bf1, acc[mt][1], 0, 0, 0);
            }
        }
        __syncthreads();
    }
#pragma unroll
    for (int nt = 0; nt < 2; ++nt) {
        int c = n0 + wn * 32 + nt * 16 + l4;
        float bv = bias[c];
#pragma unroll
        for (int mt = 0; mt < 4; ++mt) {
            int mbase = m0 + wm * 64 + mt * 16 + quad * 4;
#pragma unroll
            for (int reg = 0; reg < 4; ++reg)
                out[(size_t)(mbase + reg) * 256 + c] = acc[mt][nt][reg] + bv;
        }
    }
}

extern "C" void kernel_launch(void* const* d_in, const int* in_sizes, int n_in,
                              void* d_out, int out_size, void* d_ws, size_t ws_size,
                              hipStream_t stream)
{
    const float* feats = (const float*)d_in[0];
    const float* nco   = (const float*)d_in[1];
    const float* qkvw  = (const float*)d_in[2];
    const float* qkvb  = (const float*)d_in[3];
    const float* qxt   = (const float*)d_in[4];
    const float* kxt   = (const float*)d_in[5];
    const float* vxt   = (const float*)d_in[6];
    const float* qrt   = (const float*)d_in[7];
    const float* krt   = (const float*)d_in[8];
    const float* vrt   = (const float*)d_in[9];
    const float* pw    = (const float*)d_in[10];
    const float* pb    = (const float*)d_in[11];
    float* out = (float*)d_out;

    ushort* qb  = (ushort*)d_ws;                       // [128][8][64][32]
    ushort* kb  = qb + (size_t)2097152;
    ushort* vb  = kb + (size_t)2097152;
    ushort* aob = vb + (size_t)2097152;                // [8192][256] bf16
    ushort* cst = aob + (size_t)2097152;               // bf16 cast region
    ushort* featsB = cst;                              // 2,097,152 el
    ushort* qkvwB  = cst + (size_t)2097152;            //   196,608 el
    ushort* projwB = cst + (size_t)2293760;            //    65,536 el
    ushort* qxtB   = cst + (size_t)2359296;            //    30,720 el
    ushort* kxtB   = cst + (size_t)2390016;
    ushort* vxtB   = cst + (size_t)2420736;
    ushort* qrtB   = cst + (size_t)2451456;            //    24,576 el
    ushort* krtB   = cst + (size_t)2476032;
    ushort* vrtB   = cst + (size_t)2500608;            // end 2,525,184 el

    k_cast<<<dim3(2466), 256, 0, stream>>>(feats, qkvw, pw, qxt, kxt, vxt, qrt, krt, vrt, cst);
    k_qkv<<<dim3(12, 64), 256, 0, stream>>>(featsB, qkvwB, qkvb, qb, kb, vb);
    k_attn<<<dim3(1024), 256, 0, stream>>>(qb, kb, vb, nco, qxtB, kxtB, vxtB, qrtB, krtB, vrtB, aob);
    k_proj<<<dim3(4, 64), 256, 0, stream>>>(aob, projwB, pb, out);
}

// Round 6
// 285.368 us; speedup vs baseline: 1.1845x; 1.0747x over previous
//
#include <hip/hip_runtime.h>

// DIM=256 H=8 HD=32 W=64 N=8192 nw=128
// xyz: T=40, off=20, hi=39, R=120 (pad 128) ; rgb: T=32, off=16, hi=31, R=96
// table element ((c*T+t)*8+h)*32+d == r*256 + h*32 + d, r=c*T+t
// table sizes: xyz 120*256 = 30,720 el = 7,680 float4 ; rgb 96*256 = 24,576 el = 6,144 float4

typedef __attribute__((ext_vector_type(8))) short short8;
typedef __attribute__((ext_vector_type(4))) float f32x4;

__device__ __forceinline__ unsigned short f2bf(float f) {
    union { float f; unsigned int u; } v; v.f = f;
    unsigned int r = v.u + 0x7FFFu + ((v.u >> 16) & 1u);
    return (unsigned short)(r >> 16);
}

// ---------------------------------------------------------------------------
// Cast prepass: fp32 -> bf16 for feats, qkv_w, proj_w, 6 tables.
// ---------------------------------------------------------------------------
__global__ __launch_bounds__(256) void k_cast(
    const float* __restrict__ s0, const float* __restrict__ s1,
    const float* __restrict__ s2, const float* __restrict__ s3,
    const float* __restrict__ s4, const float* __restrict__ s5,
    const float* __restrict__ s6, const float* __restrict__ s7,
    const float* __restrict__ s8, ushort* __restrict__ dst)
{
    unsigned g = blockIdx.x * 256 + threadIdx.x;   // float4 index, < 631296
    const float* src;
    unsigned base;
    if      (g < 524288u) { src = s0; base = 0; }
    else if (g < 573440u) { src = s1; base = 524288u; }
    else if (g < 589824u) { src = s2; base = 573440u; }
    else if (g < 597504u) { src = s3; base = 589824u; }
    else if (g < 605184u) { src = s4; base = 597504u; }
    else if (g < 612864u) { src = s5; base = 605184u; }
    else if (g < 619008u) { src = s6; base = 612864u; }
    else if (g < 625152u) { src = s7; base = 619008u; }
    else                  { src = s8; base = 625152u; }
    float4 v = *(const float4*)(src + (size_t)(g - base) * 4);
    ushort4 o;
    o.x = f2bf(v.x); o.y = f2bf(v.y); o.z = f2bf(v.z); o.w = f2bf(v.w);
    *(ushort4*)(dst + (size_t)g * 4) = o;
}

// ---------------------------------------------------------------------------
// QKV GEMM (bf16 MFMA): qkv = feats @ qkv_w^T + b -> q/k/v bf16 [nw][H][W][HD]
// ---------------------------------------------------------------------------
__global__ __launch_bounds__(256) void k_qkv(
    const ushort* __restrict__ A, const ushort* __restrict__ B,
    const float* __restrict__ bias,
    ushort* __restrict__ qb, ushort* __restrict__ kb, ushort* __restrict__ vb)
{
    __shared__ __align__(16) ushort a_s[128 * 72];
    __shared__ __align__(16) ushort b_s[64 * 72];
    const int tid = threadIdx.x;
    const int m0 = blockIdx.y * 128;
    const int n0 = blockIdx.x * 64;
    const int w = tid >> 6, wm = w >> 1, wn = w & 1;
    const int l4 = tid & 15, quad = (tid >> 4) & 3;
    f32x4 acc[4][2];
#pragma unroll
    for (int mt = 0; mt < 4; ++mt)
#pragma unroll
        for (int nt = 0; nt < 2; ++nt) acc[mt][nt] = (f32x4){0.f, 0.f, 0.f, 0.f};

    for (int k0 = 0; k0 < 256; k0 += 64) {
#pragma unroll
        for (int l = 0; l < 4; ++l) {
            int e = tid + l * 256;
            int row = e >> 3, kq = e & 7;
            *(uint4*)&a_s[row * 72 + kq * 8] =
                *(const uint4*)(A + (size_t)(m0 + row) * 256 + k0 + kq * 8);
        }
#pragma unroll
        for (int l = 0; l < 2; ++l) {
            int e = tid + l * 256;
            int row = e >> 3, kq = e & 7;
            *(uint4*)&b_s[row * 72 + kq * 8] =
                *(const uint4*)(B + (size_t)(n0 + row) * 256 + k0 + kq * 8);
        }
        __syncthreads();
#pragma unroll
        for (int kh = 0; kh < 2; ++kh) {
            short8 bf0 = *(const short8*)&b_s[(wn * 32 + l4) * 72 + kh * 32 + quad * 8];
            short8 bf1 = *(const short8*)&b_s[(wn * 32 + 16 + l4) * 72 + kh * 32 + quad * 8];
#pragma unroll
            for (int mt = 0; mt < 4; ++mt) {
                short8 af = *(const short8*)&a_s[(wm * 64 + mt * 16 + l4) * 72 + kh * 32 + quad * 8];
                acc[mt][0] = __builtin_amdgcn_mfma_f32_16x16x32_bf16(af, bf0, acc[mt][0], 0, 0, 0);
                acc[mt][1] = __builtin_amdgcn_mfma_f32_16x16x32_bf16(af, bf1, acc[mt][1], 0, 0, 0);
            }
        }
        __syncthreads();
    }
#pragma unroll
    for (int nt = 0; nt < 2; ++nt) {
        int c = n0 + wn * 32 + nt * 16 + l4;
        float bv = bias[c];
        int s = c >> 8, rem = c & 255, h = rem >> 5, d = rem & 31;
        ushort* dst = (s == 0) ? qb : ((s == 1) ? kb : vb);
        float mul = (s == 0) ? 0.17677669529663687f : 1.0f;
#pragma unroll
        for (int mt = 0; mt < 4; ++mt) {
            int mbase = m0 + wm * 64 + mt * 16 + quad * 4;
#pragma unroll
            for (int reg = 0; reg < 4; ++reg) {
                int m = mbase + reg;
                int nw = m >> 6, ii = m & 63;
                dst[((size_t)((nw * 8 + h) * 64 + ii)) * 32 + d] = f2bf((acc[mt][nt][reg] + bv) * mul);
            }
        }
    }
}

// ---------------------------------------------------------------------------
// MFMA attention per (window, head). 4 waves; wave w owns rows w*16..w*16+15.
// A/B frag: [outer=lane&15][k=quad*8+j] ; C/D: col=lane&15, row=quad*4+reg.
// LDS: dbuf fp32 64x122 (31,232 B) + ushort union U (22,528 B) = 53,760 B.
// __launch_bounds__(256, 2): round-5 post-mortem — (256,3) caps the unified
// VGPR+AGPR budget at ~170/wave (split ~84+84) and forces ~650 B/thread of
// scratch spill (175 MB WRITE_SIZE). (256,2) gives 256/wave; if the compiler
// lands <=170 VGPR the HW still schedules 3 blocks/CU (LDS fits: 3x53,760 =
// 161,280 <= 163,840).
// ---------------------------------------------------------------------------
#define DBS 122

__global__ __launch_bounds__(256, 2) void k_attn(
    const ushort* __restrict__ qb, const ushort* __restrict__ kb, const ushort* __restrict__ vb,
    const float* __restrict__ nco,
    const ushort* __restrict__ qxt, const ushort* __restrict__ kxt, const ushort* __restrict__ vxt,
    const ushort* __restrict__ qrt, const ushort* __restrict__ krt, const ushort* __restrict__ vrt,
    ushort* __restrict__ aout)
{
    __shared__ __align__(16) float dbuf[64 * DBS];
    __shared__ __align__(16) ushort U[11264];
    // Phase A overlays:
    ushort* q_s  = U;              // [64][40]
    ushort* k_s  = U + 2560;       // [64][40]
    ushort* tbl  = U + 5120;       // [128][40]
    float*  cwf  = (float*)(U + 10240);  // [64][6], dead after idx precompute
    // Phase B overlays:
    ushort* attn_s = U;            // [64][72]
    ushort* v_t    = U + 4608;     // [32][72]
    ushort* vtbl   = U + 6912;     // [32][136]

    const int tid = threadIdx.x;
    const int n = blockIdx.x >> 3;
    const int h = blockIdx.x & 7;
    const int w = tid >> 6;
    const int l4 = tid & 15;
    const int quad = (tid >> 4) & 3;

    const size_t base = (size_t)((n * 8 + h) * 64) * 32;

    // ---- stage q, k, coords ----
    {
        int row = tid >> 2, part = tid & 3;
        *(uint4*)&q_s[row * 40 + part * 8] = *(const uint4*)(qb + base + tid * 8);
        *(uint4*)&k_s[row * 40 + part * 8] = *(const uint4*)(kb + base + tid * 8);
    }
    if (tid < 64) {
        const float* cp = nco + (size_t)(n * 64 + tid) * 6;
        cwf[tid * 6 + 0] = cp[0] * 4.f; cwf[tid * 6 + 1] = cp[1] * 4.f;
        cwf[tid * 6 + 2] = cp[2] * 4.f; cwf[tid * 6 + 3] = cp[3] * 8.f;
        cwf[tid * 6 + 4] = cp[4] * 8.f; cwf[tid * 6 + 5] = cp[5] * 8.f;
    }

    auto stageTbl = [&](const ushort* tbg, int R, int Rpad) {
        int r = tid >> 1, half = tid & 1;
        if (r < R) {
            const ushort* src = tbg + (size_t)r * 256 + half * 16;
            ushort* dp = &tbl[r * 40 + half * 16];
            *(uint4*)dp = *(const uint4*)src;
            *(uint4*)(dp + 8) = *(const uint4*)(src + 8);
        }
        for (int e = tid; e < (Rpad - R) * 40; e += 256) tbl[R * 40 + e] = 0;
    };
    auto stageVtbl = [&](const ushort* tbg, int R) {
        int r = tid >> 1, half = tid & 1;
        if (r < R) {
            const ushort* src = tbg + (size_t)r * 256 + half * 16;
            uint4 p0 = *(const uint4*)src, p1 = *(const uint4*)(src + 8);
            const ushort* u0 = (const ushort*)&p0;
            const ushort* u1 = (const ushort*)&p1;
#pragma unroll
            for (int ii = 0; ii < 8; ++ii) {
                vtbl[(half * 16 + ii) * 136 + r] = u0[ii];
                vtbl[(half * 16 + 8 + ii) * 136 + r] = u1[ii];
            }
        }
        int span = 128 - R;
        for (int e = tid; e < 32 * span; e += 256) {
            int d = e / span, rr = e - d * span;
            vtbl[d * 136 + R + rr] = 0;
        }
    };
    auto stageVt = [&]() {
        int j = tid >> 2, d0 = (tid & 3) * 8;
        uint4 pk = *(const uint4*)(vb + base + tid * 8);
        const ushort* u = (const ushort*)&pk;
#pragma unroll
        for (int ii = 0; ii < 8; ++ii) v_t[(d0 + ii) * 72 + j] = u[ii];
    };

    auto tgemm = [&](const ushort* a_s, int NT, int maxc) {
        short8 af = *(const short8*)&a_s[(w * 16 + l4) * 40 + quad * 8];
        for (int tt = 0; tt < NT; ++tt) {
            short8 bf = *(const short8*)&tbl[(tt * 16 + l4) * 40 + quad * 8];
            f32x4 a = {0.f, 0.f, 0.f, 0.f};
            a = __builtin_amdgcn_mfma_f32_16x16x32_bf16(af, bf, a, 0, 0, 0);
            int col = tt * 16 + l4;
            int rb = w * 16 + quad * 4;
            if (col < maxc) {
                dbuf[(rb + 0) * DBS + col] = a[0];
                dbuf[(rb + 1) * DBS + col] = a[1];
                dbuf[(rb + 2) * DBS + col] = a[2];
                dbuf[(rb + 3) * DBS + col] = a[3];
            }
        }
    };

    stageTbl(kxt + h * 32, 120, 128);
    __syncthreads();

    // ---- precompute gather/scatter indices once (packed t0|t1<<8|t2<<16) ----
    // Strictly register-resident: constant-indexed, never address-taken.
    int idxX[4][4], idxR[4][4];   // [tt][reg]
    {
#pragma unroll
        for (int tt = 0; tt < 4; ++tt) {
            int j = tt * 16 + l4;
            float cj0 = cwf[j * 6 + 0], cj1 = cwf[j * 6 + 1], cj2 = cwf[j * 6 + 2];
            float cj3 = cwf[j * 6 + 3], cj4 = cwf[j * 6 + 4], cj5 = cwf[j * 6 + 5];
#pragma unroll
            for (int reg = 0; reg < 4; ++reg) {
                int i = w * 16 + quad * 4 + reg;
                int x0 = min(max((int)floorf(cwf[i * 6 + 0] - cj0) + 20, 0), 39);
                int x1 = min(max((int)floorf(cwf[i * 6 + 1] - cj1) + 20, 0), 39);
                int x2 = min(max((int)floorf(cwf[i * 6 + 2] - cj2) + 20, 0), 39);
                idxX[tt][reg] = x0 | (x1 << 8) | (x2 << 16);
                int r0 = min(max((int)floorf(cwf[i * 6 + 3] - cj3) + 16, 0), 31);
                int r1 = min(max((int)floorf(cwf[i * 6 + 4] - cj4) + 16, 0), 31);
                int r2 = min(max((int)floorf(cwf[i * 6 + 5] - cj5) + 16, 0), 31);
                idxR[tt][reg] = r0 | (r1 << 8) | (r2 << 16);
            }
        }
    }

    float lg[4][4];   // [tt][reg]: row i = w*16+quad*4+reg, col j = tt*16+l4

    auto gatherX = [&](bool useJ) {
#pragma unroll
        for (int tt = 0; tt < 4; ++tt) {
#pragma unroll
            for (int reg = 0; reg < 4; ++reg) {
                int p = idxX[tt][reg];
                int b = (useJ ? (tt * 16 + l4) : (w * 16 + quad * 4 + reg)) * DBS;
                lg[tt][reg] += dbuf[b + (p & 255)] + dbuf[b + 40 + ((p >> 8) & 255)]
                             + dbuf[b + 80 + (p >> 16)];
            }
        }
    };
    auto gatherR = [&](bool useJ) {
#pragma unroll
        for (int tt = 0; tt < 4; ++tt) {
#pragma unroll
            for (int reg = 0; reg < 4; ++reg) {
                int p = idxR[tt][reg];
                int b = (useJ ? (tt * 16 + l4) : (w * 16 + quad * 4 + reg)) * DBS;
                lg[tt][reg] += dbuf[b + (p & 255)] + dbuf[b + 32 + ((p >> 8) & 255)]
                             + dbuf[b + 64 + (p >> 16)];
            }
        }
    };
    auto scatterX = [&]() {
#pragma unroll
        for (int reg = 0; reg < 4; ++reg) {
            float* bi = &dbuf[(w * 16 + quad * 4 + reg) * DBS];
#pragma unroll
            for (int tt = 0; tt < 4; ++tt) {
                int p = idxX[tt][reg];
                float a = lg[tt][reg];
                atomicAdd(bi + (p & 255), a);
                atomicAdd(bi + 40 + ((p >> 8) & 255), a);
                atomicAdd(bi + 80 + (p >> 16), a);
            }
        }
    };
    auto scatterR = [&]() {
#pragma unroll
        for (int reg = 0; reg < 4; ++reg) {
            float* bi = &dbuf[(w * 16 + quad * 4 + reg) * DBS];
#pragma unroll
            for (int tt = 0; tt < 4; ++tt) {
                int p = idxR[tt][reg];
                float a = lg[tt][reg];
                atomicAdd(bi + (p & 255), a);
                atomicAdd(bi + 32 + ((p >> 8) & 255), a);
                atomicAdd(bi + 64 + (p >> 16), a);
            }
        }
    };
    auto zeroBins = [&]() {
        float4 z = {0.f, 0.f, 0.f, 0.f};
        for (int e = tid * 4; e < 64 * DBS; e += 1024) *(float4*)&dbuf[e] = z;
    };

    // ---- QK logits + dk_xyz ----
    {
        short8 aq = *(const short8*)&q_s[(w * 16 + l4) * 40 + quad * 8];
#pragma unroll
        for (int tt = 0; tt < 4; ++tt) {
            short8 bk = *(const short8*)&k_s[(tt * 16 + l4) * 40 + quad * 8];
            f32x4 r = {0.f, 0.f, 0.f, 0.f};
            r = __builtin_amdgcn_mfma_f32_16x16x32_bf16(aq, bk, r, 0, 0, 0);
            lg[tt][0] = r[0]; lg[tt][1] = r[1]; lg[tt][2] = r[2]; lg[tt][3] = r[3];
        }
    }
    tgemm(k_s, 8, 120);                  // dk_xyz
    __syncthreads();
    gatherX(true);                       // bias_k xyz
    stageTbl(krt + h * 32, 96, 96);
    __syncthreads();
    tgemm(k_s, 6, 96);                   // dk_rgb
    __syncthreads();
    gatherR(true);                       // bias_k rgb
    stageTbl(qxt + h * 32, 120, 128);
    __syncthreads();
    tgemm(q_s, 8, 120);                  // dq_xyz
    __syncthreads();
    gatherX(false);                      // bias_q xyz
    stageTbl(qrt + h * 32, 96, 96);
    __syncthreads();
    tgemm(q_s, 6, 96);                   // dq_rgb
    __syncthreads();
    gatherR(false);                      // bias_q rgb
    stageVtbl(vxt + h * 32, 120);        // tbl + cw regions dead now
    stageVt();                           // k_s tail dead now
    __syncthreads();

    // ---- softmax ----
#pragma unroll
    for (int reg = 0; reg < 4; ++reg) {
        float m = fmaxf(fmaxf(lg[0][reg], lg[1][reg]), fmaxf(lg[2][reg], lg[3][reg]));
        m = fmaxf(m, __shfl_xor(m, 1));
        m = fmaxf(m, __shfl_xor(m, 2));
        m = fmaxf(m, __shfl_xor(m, 4));
        m = fmaxf(m, __shfl_xor(m, 8));
        float s = 0.f;
#pragma unroll
        for (int tt = 0; tt < 4; ++tt) { lg[tt][reg] = __expf(lg[tt][reg] - m); s += lg[tt][reg]; }
        s += __shfl_xor(s, 1); s += __shfl_xor(s, 2);
        s += __shfl_xor(s, 4); s += __shfl_xor(s, 8);
        float inv = 1.f / s;
#pragma unroll
        for (int tt = 0; tt < 4; ++tt) lg[tt][reg] *= inv;
    }
#pragma unroll
    for (int tt = 0; tt < 4; ++tt)
#pragma unroll
        for (int reg = 0; reg < 4; ++reg)
            attn_s[(w * 16 + quad * 4 + reg) * 72 + tt * 16 + l4] = f2bf(lg[tt][reg]);
    zeroBins();
    __syncthreads();

    // ---- scatter xyz bins + AV ----
    scatterX();
    f32x4 acc0 = {0.f, 0.f, 0.f, 0.f}, acc1 = {0.f, 0.f, 0.f, 0.f};
#pragma unroll
    for (int s = 0; s < 2; ++s) {
        short8 af = *(const short8*)&attn_s[(w * 16 + l4) * 72 + s * 32 + quad * 8];
        short8 b0 = *(const short8*)&v_t[l4 * 72 + s * 32 + quad * 8];
        short8 b1 = *(const short8*)&v_t[(16 + l4) * 72 + s * 32 + quad * 8];
        acc0 = __builtin_amdgcn_mfma_f32_16x16x32_bf16(af, b0, acc0, 0, 0, 0);
        acc1 = __builtin_amdgcn_mfma_f32_16x16x32_bf16(af, b1, acc1, 0, 0, 0);
    }
    __syncthreads();

    auto atgemm = [&](int Rlim) {
#pragma unroll
        for (int s = 0; s < 4; ++s) {
            int koff = s * 32 + quad * 8;
            short8 af = {0, 0, 0, 0, 0, 0, 0, 0};
            if (koff < Rlim) {
                const float* ap = &dbuf[(w * 16 + l4) * DBS + koff];
#pragma unroll
                for (int ii = 0; ii < 8; ++ii) af[ii] = (short)f2bf(ap[ii]);
            }
            short8 b0 = *(const short8*)&vtbl[l4 * 136 + koff];
            short8 b1 = *(const short8*)&vtbl[(16 + l4) * 136 + koff];
            acc0 = __builtin_amdgcn_mfma_f32_16x16x32_bf16(af, b0, acc0, 0, 0, 0);
            acc1 = __builtin_amdgcn_mfma_f32_16x16x32_bf16(af, b1, acc1, 0, 0, 0);
        }
    };
    atgemm(120);                         // value-bias xyz
    __syncthreads();
    zeroBins();
    stageVtbl(vrt + h * 32, 96);
    __syncthreads();
    scatterR();
    __syncthreads();
    atgemm(96);                          // value-bias rgb

    // ---- epilogue: bf16 ao[i][h*32+d] ----
    {
        ushort* op = aout + (size_t)(n * 64 + w * 16 + quad * 4) * 256 + h * 32;
#pragma unroll
        for (int reg = 0; reg < 4; ++reg) {
            op[reg * 256 + l4] = f2bf(acc0[reg]);
            op[reg * 256 + 16 + l4] = f2bf(acc1[reg]);
        }
    }
}

// ---------------------------------------------------------------------------
// Proj GEMM (bf16 MFMA): out = ao @ proj_w^T + proj_b (fp32 out)
// ---------------------------------------------------------------------------
__global__ __launch_bounds__(256) void k_proj(
    const ushort* __restrict__ A, const ushort* __restrict__ B,
    const float* __restrict__ bias, float* __restrict__ out)
{
    __shared__ __align__(16) ushort a_s[128 * 72];
    __shared__ __align__(16) ushort b_s[64 * 72];
    const int tid = threadIdx.x;
    const int m0 = blockIdx.y * 128;
    const int n0 = blockIdx.x * 64;
    const int w = tid >> 6, wm = w >> 1, wn = w & 1;
    const int l4 = tid & 15, quad = (tid >> 4) & 3;
    f32x4 acc[4][2];
#pragma unroll
    for (int mt = 0; mt < 4; ++mt)
#pragma unroll
        for (int nt = 0; nt < 2; ++nt) acc[mt][nt] = (f32x4){0.f, 0.f, 0.f, 0.f};

    for (int k0 = 0; k0 < 256; k0 += 64) {
#pragma unroll
        for (int l = 0; l < 4; ++l) {
            int e = tid + l * 256;
            int row = e >> 3, kq = e & 7;
            *(uint4*)&a_s[row * 72 + kq * 8] =
                *(const uint4*)(A + (size_t)(m0 + row) * 256 + k0 + kq * 8);
        }
#pragma unroll
        for (int l = 0; l < 2; ++l) {
            int e = tid + l * 256;
            int row = e >> 3, kq = e & 7;
            *(uint4*)&b_s[row * 72 + kq * 8] =
                *(const uint4*)(B + (size_t)(n0 + row) * 256 + k0 + kq * 8);
        }
        __syncthreads();
#pragma unroll
        for (int kh = 0; kh < 2; ++kh) {
            short8 bf0 = *(const short8*)&b_s[(wn * 32 + l4) * 72 + kh * 32 + quad * 8];
            short8 bf1 = *(const short8*)&b_s[(wn * 32 + 16 + l4) * 72 + kh * 32 + quad * 8];
#pragma unroll
            for (int mt = 0; mt < 4; ++mt) {
                short8 af = *(const short8*)&a_s[(wm * 64 + mt * 16 + l4) * 72 + kh * 32 + quad * 8];
                acc[mt][0] = __builtin_amdgcn_mfma_f32_16x16x32_bf16(af, bf0, acc[mt][0], 0, 0, 0);
                acc[mt][1] = __builtin_amdgcn_mfma_f32_16x16x32_bf16(af, bf1, acc[mt][1], 0, 0, 0);
            }
        }
        __syncthreads();
    }
#pragma unroll
    for (int nt = 0; nt < 2; ++nt) {
        int c = n0 + wn * 32 + nt * 16 + l4;
        float bv = bias[c];
#pragma unroll
        for (int mt = 0; mt < 4; ++mt) {
            int mbase = m0 + wm * 64 + mt * 16 + quad * 4;
#pragma unroll
            for (int reg = 0; reg < 4; ++reg)
                out[(size_t)(mbase + reg) * 256 + c] = acc[mt][nt][reg] + bv;
        }
    }
}

extern "C" void kernel_launch(void* const* d_in, const int* in_sizes, int n_in,
                              void* d_out, int out_size, void* d_ws, size_t ws_size,
                              hipStream_t stream)
{
    const float* feats = (const float*)d_in[0];
    const float* nco   = (const float*)d_in[1];
    const float* qkvw  = (const float*)d_in[2];
    const float* qkvb  = (const float*)d_in[3];
    const float* qxt   = (const float*)d_in[4];
    const float* kxt   = (const float*)d_in[5];
    const float* vxt   = (const float*)d_in[6];
    const float* qrt   = (const float*)d_in[7];
    const float* krt   = (const float*)d_in[8];
    const float* vrt   = (const float*)d_in[9];
    const float* pw    = (const float*)d_in[10];
    const float* pb    = (const float*)d_in[11];
    float* out = (float*)d_out;

    ushort* qb  = (ushort*)d_ws;                       // [128][8][64][32]
    ushort* kb  = qb + (size_t)2097152;
    ushort* vb  = kb + (size_t)2097152;
    ushort* aob = vb + (size_t)2097152;                // [8192][256] bf16
    ushort* cst = aob + (size_t)2097152;               // bf16 cast region
    ushort* featsB = cst;                              // 2,097,152 el
    ushort* qkvwB  = cst + (size_t)2097152;            //   196,608 el
    ushort* projwB = cst + (size_t)2293760;            //    65,536 el
    ushort* qxtB   = cst + (size_t)2359296;            //    30,720 el
    ushort* kxtB   = cst + (size_t)2390016;
    ushort* vxtB   = cst + (size_t)2420736;
    ushort* qrtB   = cst + (size_t)2451456;            //    24,576 el
    ushort* krtB   = cst + (size_t)2476032;
    ushort* vrtB   = cst + (size_t)2500608;            // end 2,525,184 el

    k_cast<<<dim3(2466), 256, 0, stream>>>(feats, qkvw, pw, qxt, kxt, vxt, qrt, krt, vrt, cst);
    k_qkv<<<dim3(12, 64), 256, 0, stream>>>(featsB, qkvwB, qkvb, qb, kb, vb);
    k_attn<<<dim3(1024), 256, 0, stream>>>(qb, kb, vb, nco, qxtB, kxtB, vxtB, qrtB, krtB, vrtB, aob);
    k_proj<<<dim3(4, 64), 256, 0, stream>>>(aob, projwB, pb, out);
}

// Round 7
// 276.370 us; speedup vs baseline: 1.2230x; 1.0326x over previous
//
#include <hip/hip_runtime.h>

// DIM=256 H=8 HD=32 W=64 N=8192 nw=128
// xyz: T=40, off=20, hi=39, R=120 (pad 128) ; rgb: T=32, off=16, hi=31, R=96
// table element ((c*T+t)*8+h)*32+d == r*256 + h*32 + d, r=c*T+t
// table sizes: xyz 120*256 = 30,720 el = 7,680 float4 ; rgb 96*256 = 24,576 el = 6,144 float4

typedef __attribute__((ext_vector_type(8))) short short8;
typedef __attribute__((ext_vector_type(4))) float f32x4;

__device__ __forceinline__ unsigned short f2bf(float f) {
    union { float f; unsigned int u; } v; v.f = f;
    unsigned int r = v.u + 0x7FFFu + ((v.u >> 16) & 1u);
    return (unsigned short)(r >> 16);
}

// ---------------------------------------------------------------------------
// Cast prepass: fp32 -> bf16 for feats, qkv_w, proj_w, 6 tables.
// ---------------------------------------------------------------------------
__global__ __launch_bounds__(256) void k_cast(
    const float* __restrict__ s0, const float* __restrict__ s1,
    const float* __restrict__ s2, const float* __restrict__ s3,
    const float* __restrict__ s4, const float* __restrict__ s5,
    const float* __restrict__ s6, const float* __restrict__ s7,
    const float* __restrict__ s8, ushort* __restrict__ dst)
{
    unsigned g = blockIdx.x * 256 + threadIdx.x;   // float4 index, < 631296
    const float* src;
    unsigned base;
    if      (g < 524288u) { src = s0; base = 0; }
    else if (g < 573440u) { src = s1; base = 524288u; }
    else if (g < 589824u) { src = s2; base = 573440u; }
    else if (g < 597504u) { src = s3; base = 589824u; }
    else if (g < 605184u) { src = s4; base = 597504u; }
    else if (g < 612864u) { src = s5; base = 605184u; }
    else if (g < 619008u) { src = s6; base = 612864u; }
    else if (g < 625152u) { src = s7; base = 619008u; }
    else                  { src = s8; base = 625152u; }
    float4 v = *(const float4*)(src + (size_t)(g - base) * 4);
    ushort4 o;
    o.x = f2bf(v.x); o.y = f2bf(v.y); o.z = f2bf(v.z); o.w = f2bf(v.w);
    *(ushort4*)(dst + (size_t)g * 4) = o;
}

// ---------------------------------------------------------------------------
// QKV GEMM (bf16 MFMA): qkv = feats @ qkv_w^T + b -> q/k/v bf16 [nw][H][W][HD]
// ---------------------------------------------------------------------------
__global__ __launch_bounds__(256) void k_qkv(
    const ushort* __restrict__ A, const ushort* __restrict__ B,
    const float* __restrict__ bias,
    ushort* __restrict__ qb, ushort* __restrict__ kb, ushort* __restrict__ vb)
{
    __shared__ __align__(16) ushort a_s[128 * 72];
    __shared__ __align__(16) ushort b_s[64 * 72];
    const int tid = threadIdx.x;
    const int m0 = blockIdx.y * 128;
    const int n0 = blockIdx.x * 64;
    const int w = tid >> 6, wm = w >> 1, wn = w & 1;
    const int l4 = tid & 15, quad = (tid >> 4) & 3;
    f32x4 acc[4][2];
#pragma unroll
    for (int mt = 0; mt < 4; ++mt)
#pragma unroll
        for (int nt = 0; nt < 2; ++nt) acc[mt][nt] = (f32x4){0.f, 0.f, 0.f, 0.f};

    for (int k0 = 0; k0 < 256; k0 += 64) {
#pragma unroll
        for (int l = 0; l < 4; ++l) {
            int e = tid + l * 256;
            int row = e >> 3, kq = e & 7;
            *(uint4*)&a_s[row * 72 + kq * 8] =
                *(const uint4*)(A + (size_t)(m0 + row) * 256 + k0 + kq * 8);
        }
#pragma unroll
        for (int l = 0; l < 2; ++l) {
            int e = tid + l * 256;
            int row = e >> 3, kq = e & 7;
            *(uint4*)&b_s[row * 72 + kq * 8] =
                *(const uint4*)(B + (size_t)(n0 + row) * 256 + k0 + kq * 8);
        }
        __syncthreads();
#pragma unroll
        for (int kh = 0; kh < 2; ++kh) {
            short8 bf0 = *(const short8*)&b_s[(wn * 32 + l4) * 72 + kh * 32 + quad * 8];
            short8 bf1 = *(const short8*)&b_s[(wn * 32 + 16 + l4) * 72 + kh * 32 + quad * 8];
#pragma unroll
            for (int mt = 0; mt < 4; ++mt) {
                short8 af = *(const short8*)&a_s[(wm * 64 + mt * 16 + l4) * 72 + kh * 32 + quad * 8];
                acc[mt][0] = __builtin_amdgcn_mfma_f32_16x16x32_bf16(af, bf0, acc[mt][0], 0, 0, 0);
                acc[mt][1] = __builtin_amdgcn_mfma_f32_16x16x32_bf16(af, bf1, acc[mt][1], 0, 0, 0);
            }
        }
        __syncthreads();
    }
#pragma unroll
    for (int nt = 0; nt < 2; ++nt) {
        int c = n0 + wn * 32 + nt * 16 + l4;
        float bv = bias[c];
        int s = c >> 8, rem = c & 255, h = rem >> 5, d = rem & 31;
        ushort* dst = (s == 0) ? qb : ((s == 1) ? kb : vb);
        float mul = (s == 0) ? 0.17677669529663687f : 1.0f;
#pragma unroll
        for (int mt = 0; mt < 4; ++mt) {
            int mbase = m0 + wm * 64 + mt * 16 + quad * 4;
#pragma unroll
            for (int reg = 0; reg < 4; ++reg) {
                int m = mbase + reg;
                int nw = m >> 6, ii = m & 63;
                dst[((size_t)((nw * 8 + h) * 64 + ii)) * 32 + d] = f2bf((acc[mt][nt][reg] + bv) * mul);
            }
        }
    }
}

// ---------------------------------------------------------------------------
// MFMA attention per (window, head). 4 waves; wave w owns rows w*16..w*16+15.
// A/B frag: [outer=lane&15][k=quad*8+j] ; C/D: col=lane&15, row=quad*4+reg.
// LDS: dbuf fp32 64x122 (31,232 B) + ushort union U (22,528 B) = 53,760 B.
// NO min-waves in __launch_bounds__: rounds 4-6 post-mortem — any min-waves
// arg makes the compiler pin arch VGPRs to a round quantum (84 @ min=3,
// 128 @ min=2) and spill the excess (~75-170 MB scratch WRITE_SIZE). This
// kernel needs ~160 arch VGPRs; unrestricted allocation avoids all spill and
// HW still gives 3 waves/EU if the count lands <= 170.
// ---------------------------------------------------------------------------
#define DBS 122

__global__ __launch_bounds__(256) void k_attn(
    const ushort* __restrict__ qb, const ushort* __restrict__ kb, const ushort* __restrict__ vb,
    const float* __restrict__ nco,
    const ushort* __restrict__ qxt, const ushort* __restrict__ kxt, const ushort* __restrict__ vxt,
    const ushort* __restrict__ qrt, const ushort* __restrict__ krt, const ushort* __restrict__ vrt,
    ushort* __restrict__ aout)
{
    __shared__ __align__(16) float dbuf[64 * DBS];
    __shared__ __align__(16) ushort U[11264];
    // Phase A overlays:
    ushort* q_s  = U;              // [64][40]
    ushort* k_s  = U + 2560;       // [64][40]
    ushort* tbl  = U + 5120;       // [128][40]
    float*  cwf  = (float*)(U + 10240);  // [64][6], dead after idx precompute
    // Phase B overlays:
    ushort* attn_s = U;            // [64][72]
    ushort* v_t    = U + 4608;     // [32][72]
    ushort* vtbl   = U + 6912;     // [32][136]

    const int tid = threadIdx.x;
    const int n = blockIdx.x >> 3;
    const int h = blockIdx.x & 7;
    const int w = tid >> 6;
    const int l4 = tid & 15;
    const int quad = (tid >> 4) & 3;

    const size_t base = (size_t)((n * 8 + h) * 64) * 32;

    // ---- stage q, k, coords ----
    {
        int row = tid >> 2, part = tid & 3;
        *(uint4*)&q_s[row * 40 + part * 8] = *(const uint4*)(qb + base + tid * 8);
        *(uint4*)&k_s[row * 40 + part * 8] = *(const uint4*)(kb + base + tid * 8);
    }
    if (tid < 64) {
        const float* cp = nco + (size_t)(n * 64 + tid) * 6;
        cwf[tid * 6 + 0] = cp[0] * 4.f; cwf[tid * 6 + 1] = cp[1] * 4.f;
        cwf[tid * 6 + 2] = cp[2] * 4.f; cwf[tid * 6 + 3] = cp[3] * 8.f;
        cwf[tid * 6 + 4] = cp[4] * 8.f; cwf[tid * 6 + 5] = cp[5] * 8.f;
    }

    auto stageTbl = [&](const ushort* tbg, int R, int Rpad) {
        int r = tid >> 1, half = tid & 1;
        if (r < R) {
            const ushort* src = tbg + (size_t)r * 256 + half * 16;
            ushort* dp = &tbl[r * 40 + half * 16];
            *(uint4*)dp = *(const uint4*)src;
            *(uint4*)(dp + 8) = *(const uint4*)(src + 8);
        }
        for (int e = tid; e < (Rpad - R) * 40; e += 256) tbl[R * 40 + e] = 0;
    };
    auto stageVtbl = [&](const ushort* tbg, int R) {
        int r = tid >> 1, half = tid & 1;
        if (r < R) {
            const ushort* src = tbg + (size_t)r * 256 + half * 16;
            uint4 p0 = *(const uint4*)src, p1 = *(const uint4*)(src + 8);
            const ushort* u0 = (const ushort*)&p0;
            const ushort* u1 = (const ushort*)&p1;
#pragma unroll
            for (int ii = 0; ii < 8; ++ii) {
                vtbl[(half * 16 + ii) * 136 + r] = u0[ii];
                vtbl[(half * 16 + 8 + ii) * 136 + r] = u1[ii];
            }
        }
        int span = 128 - R;
        for (int e = tid; e < 32 * span; e += 256) {
            int d = e / span, rr = e - d * span;
            vtbl[d * 136 + R + rr] = 0;
        }
    };
    auto stageVt = [&]() {
        int j = tid >> 2, d0 = (tid & 3) * 8;
        uint4 pk = *(const uint4*)(vb + base + tid * 8);
        const ushort* u = (const ushort*)&pk;
#pragma unroll
        for (int ii = 0; ii < 8; ++ii) v_t[(d0 + ii) * 72 + j] = u[ii];
    };

    auto tgemm = [&](const ushort* a_s, int NT, int maxc) {
        short8 af = *(const short8*)&a_s[(w * 16 + l4) * 40 + quad * 8];
        for (int tt = 0; tt < NT; ++tt) {
            short8 bf = *(const short8*)&tbl[(tt * 16 + l4) * 40 + quad * 8];
            f32x4 a = {0.f, 0.f, 0.f, 0.f};
            a = __builtin_amdgcn_mfma_f32_16x16x32_bf16(af, bf, a, 0, 0, 0);
            int col = tt * 16 + l4;
            int rb = w * 16 + quad * 4;
            if (col < maxc) {
                dbuf[(rb + 0) * DBS + col] = a[0];
                dbuf[(rb + 1) * DBS + col] = a[1];
                dbuf[(rb + 2) * DBS + col] = a[2];
                dbuf[(rb + 3) * DBS + col] = a[3];
            }
        }
    };

    stageTbl(kxt + h * 32, 120, 128);
    __syncthreads();

    // ---- precompute gather/scatter indices once (packed t0|t1<<8|t2<<16) ----
    // Strictly register-resident: constant-indexed, never address-taken.
    int idxX[4][4], idxR[4][4];   // [tt][reg]
    {
#pragma unroll
        for (int tt = 0; tt < 4; ++tt) {
            int j = tt * 16 + l4;
            float cj0 = cwf[j * 6 + 0], cj1 = cwf[j * 6 + 1], cj2 = cwf[j * 6 + 2];
            float cj3 = cwf[j * 6 + 3], cj4 = cwf[j * 6 + 4], cj5 = cwf[j * 6 + 5];
#pragma unroll
            for (int reg = 0; reg < 4; ++reg) {
                int i = w * 16 + quad * 4 + reg;
                int x0 = min(max((int)floorf(cwf[i * 6 + 0] - cj0) + 20, 0), 39);
                int x1 = min(max((int)floorf(cwf[i * 6 + 1] - cj1) + 20, 0), 39);
                int x2 = min(max((int)floorf(cwf[i * 6 + 2] - cj2) + 20, 0), 39);
                idxX[tt][reg] = x0 | (x1 << 8) | (x2 << 16);
                int r0 = min(max((int)floorf(cwf[i * 6 + 3] - cj3) + 16, 0), 31);
                int r1 = min(max((int)floorf(cwf[i * 6 + 4] - cj4) + 16, 0), 31);
                int r2 = min(max((int)floorf(cwf[i * 6 + 5] - cj5) + 16, 0), 31);
                idxR[tt][reg] = r0 | (r1 << 8) | (r2 << 16);
            }
        }
    }

    float lg[4][4];   // [tt][reg]: row i = w*16+quad*4+reg, col j = tt*16+l4

    auto gatherX = [&](bool useJ) {
#pragma unroll
        for (int tt = 0; tt < 4; ++tt) {
#pragma unroll
            for (int reg = 0; reg < 4; ++reg) {
                int p = idxX[tt][reg];
                int b = (useJ ? (tt * 16 + l4) : (w * 16 + quad * 4 + reg)) * DBS;
                lg[tt][reg] += dbuf[b + (p & 255)] + dbuf[b + 40 + ((p >> 8) & 255)]
                             + dbuf[b + 80 + (p >> 16)];
            }
        }
    };
    auto gatherR = [&](bool useJ) {
#pragma unroll
        for (int tt = 0; tt < 4; ++tt) {
#pragma unroll
            for (int reg = 0; reg < 4; ++reg) {
                int p = idxR[tt][reg];
                int b = (useJ ? (tt * 16 + l4) : (w * 16 + quad * 4 + reg)) * DBS;
                lg[tt][reg] += dbuf[b + (p & 255)] + dbuf[b + 32 + ((p >> 8) & 255)]
                             + dbuf[b + 64 + (p >> 16)];
            }
        }
    };
    auto scatterX = [&]() {
#pragma unroll
        for (int reg = 0; reg < 4; ++reg) {
            float* bi = &dbuf[(w * 16 + quad * 4 + reg) * DBS];
#pragma unroll
            for (int tt = 0; tt < 4; ++tt) {
                int p = idxX[tt][reg];
                float a = lg[tt][reg];
                atomicAdd(bi + (p & 255), a);
                atomicAdd(bi + 40 + ((p >> 8) & 255), a);
                atomicAdd(bi + 80 + (p >> 16), a);
            }
        }
    };
    auto scatterR = [&]() {
#pragma unroll
        for (int reg = 0; reg < 4; ++reg) {
            float* bi = &dbuf[(w * 16 + quad * 4 + reg) * DBS];
#pragma unroll
            for (int tt = 0; tt < 4; ++tt) {
                int p = idxR[tt][reg];
                float a = lg[tt][reg];
                atomicAdd(bi + (p & 255), a);
                atomicAdd(bi + 32 + ((p >> 8) & 255), a);
                atomicAdd(bi + 64 + (p >> 16), a);
            }
        }
    };
    auto zeroBins = [&]() {
        float4 z = {0.f, 0.f, 0.f, 0.f};
        for (int e = tid * 4; e < 64 * DBS; e += 1024) *(float4*)&dbuf[e] = z;
    };

    // ---- QK logits + dk_xyz ----
    {
        short8 aq = *(const short8*)&q_s[(w * 16 + l4) * 40 + quad * 8];
#pragma unroll
        for (int tt = 0; tt < 4; ++tt) {
            short8 bk = *(const short8*)&k_s[(tt * 16 + l4) * 40 + quad * 8];
            f32x4 r = {0.f, 0.f, 0.f, 0.f};
            r = __builtin_amdgcn_mfma_f32_16x16x32_bf16(aq, bk, r, 0, 0, 0);
            lg[tt][0] = r[0]; lg[tt][1] = r[1]; lg[tt][2] = r[2]; lg[tt][3] = r[3];
        }
    }
    tgemm(k_s, 8, 120);                  // dk_xyz
    __syncthreads();
    gatherX(true);                       // bias_k xyz
    stageTbl(krt + h * 32, 96, 96);
    __syncthreads();
    tgemm(k_s, 6, 96);                   // dk_rgb
    __syncthreads();
    gatherR(true);                       // bias_k rgb
    stageTbl(qxt + h * 32, 120, 128);
    __syncthreads();
    tgemm(q_s, 8, 120);                  // dq_xyz
    __syncthreads();
    gatherX(false);                      // bias_q xyz
    stageTbl(qrt + h * 32, 96, 96);
    __syncthreads();
    tgemm(q_s, 6, 96);                   // dq_rgb
    __syncthreads();
    gatherR(false);                      // bias_q rgb
    stageVtbl(vxt + h * 32, 120);        // tbl + cw regions dead now
    stageVt();                           // k_s tail dead now
    __syncthreads();

    // ---- softmax ----
#pragma unroll
    for (int reg = 0; reg < 4; ++reg) {
        float m = fmaxf(fmaxf(lg[0][reg], lg[1][reg]), fmaxf(lg[2][reg], lg[3][reg]));
        m = fmaxf(m, __shfl_xor(m, 1));
        m = fmaxf(m, __shfl_xor(m, 2));
        m = fmaxf(m, __shfl_xor(m, 4));
        m = fmaxf(m, __shfl_xor(m, 8));
        float s = 0.f;
#pragma unroll
        for (int tt = 0; tt < 4; ++tt) { lg[tt][reg] = __expf(lg[tt][reg] - m); s += lg[tt][reg]; }
        s += __shfl_xor(s, 1); s += __shfl_xor(s, 2);
        s += __shfl_xor(s, 4); s += __shfl_xor(s, 8);
        float inv = 1.f / s;
#pragma unroll
        for (int tt = 0; tt < 4; ++tt) lg[tt][reg] *= inv;
    }
#pragma unroll
    for (int tt = 0; tt < 4; ++tt)
#pragma unroll
        for (int reg = 0; reg < 4; ++reg)
            attn_s[(w * 16 + quad * 4 + reg) * 72 + tt * 16 + l4] = f2bf(lg[tt][reg]);
    zeroBins();
    __syncthreads();

    // ---- scatter xyz bins + AV ----
    scatterX();
    f32x4 acc0 = {0.f, 0.f, 0.f, 0.f}, acc1 = {0.f, 0.f, 0.f, 0.f};
#pragma unroll
    for (int s = 0; s < 2; ++s) {
        short8 af = *(const short8*)&attn_s[(w * 16 + l4) * 72 + s * 32 + quad * 8];
        short8 b0 = *(const short8*)&v_t[l4 * 72 + s * 32 + quad * 8];
        short8 b1 = *(const short8*)&v_t[(16 + l4) * 72 + s * 32 + quad * 8];
        acc0 = __builtin_amdgcn_mfma_f32_16x16x32_bf16(af, b0, acc0, 0, 0, 0);
        acc1 = __builtin_amdgcn_mfma_f32_16x16x32_bf16(af, b1, acc1, 0, 0, 0);
    }
    __syncthreads();

    auto atgemm = [&](int Rlim) {
#pragma unroll
        for (int s = 0; s < 4; ++s) {
            int koff = s * 32 + quad * 8;
            short8 af = {0, 0, 0, 0, 0, 0, 0, 0};
            if (koff < Rlim) {
                const float* ap = &dbuf[(w * 16 + l4) * DBS + koff];
#pragma unroll
                for (int ii = 0; ii < 8; ++ii) af[ii] = (short)f2bf(ap[ii]);
            }
            short8 b0 = *(const short8*)&vtbl[l4 * 136 + koff];
            short8 b1 = *(const short8*)&vtbl[(16 + l4) * 136 + koff];
            acc0 = __builtin_amdgcn_mfma_f32_16x16x32_bf16(af, b0, acc0, 0, 0, 0);
            acc1 = __builtin_amdgcn_mfma_f32_16x16x32_bf16(af, b1, acc1, 0, 0, 0);
        }
    };
    atgemm(120);                         // value-bias xyz
    __syncthreads();
    zeroBins();
    stageVtbl(vrt + h * 32, 96);
    __syncthreads();
    scatterR();
    __syncthreads();
    atgemm(96);                          // value-bias rgb

    // ---- epilogue: bf16 ao[i][h*32+d] ----
    {
        ushort* op = aout + (size_t)(n * 64 + w * 16 + quad * 4) * 256 + h * 32;
#pragma unroll
        for (int reg = 0; reg < 4; ++reg) {
            op[reg * 256 + l4] = f2bf(acc0[reg]);
            op[reg * 256 + 16 + l4] = f2bf(acc1[reg]);
        }
    }
}

// ---------------------------------------------------------------------------
// Proj GEMM (bf16 MFMA): out = ao @ proj_w^T + proj_b (fp32 out)
// ---------------------------------------------------------------------------
__global__ __launch_bounds__(256) void k_proj(
    const ushort* __restrict__ A, const ushort* __restrict__ B,
    const float* __restrict__ bias, float* __restrict__ out)
{
    __shared__ __align__(16) ushort a_s[128 * 72];
    __shared__ __align__(16) ushort b_s[64 * 72];
    const int tid = threadIdx.x;
    const int m0 = blockIdx.y * 128;
    const int n0 = blockIdx.x * 64;
    const int w = tid >> 6, wm = w >> 1, wn = w & 1;
    const int l4 = tid & 15, quad = (tid >> 4) & 3;
    f32x4 acc[4][2];
#pragma unroll
    for (int mt = 0; mt < 4; ++mt)
#pragma unroll
        for (int nt = 0; nt < 2; ++nt) acc[mt][nt] = (f32x4){0.f, 0.f, 0.f, 0.f};

    for (int k0 = 0; k0 < 256; k0 += 64) {
#pragma unroll
        for (int l = 0; l < 4; ++l) {
            int e = tid + l * 256;
            int row = e >> 3, kq = e & 7;
            *(uint4*)&a_s[row * 72 + kq * 8] =
                *(const uint4*)(A + (size_t)(m0 + row) * 256 + k0 + kq * 8);
        }
#pragma unroll
        for (int l = 0; l < 2; ++l) {
            int e = tid + l * 256;
            int row = e >> 3, kq = e & 7;
            *(uint4*)&b_s[row * 72 + kq * 8] =
                *(const uint4*)(B + (size_t)(n0 + row) * 256 + k0 + kq * 8);
        }
        __syncthreads();
#pragma unroll
        for (int kh = 0; kh < 2; ++kh) {
            short8 bf0 = *(const short8*)&b_s[(wn * 32 + l4) * 72 + kh * 32 + quad * 8];
            short8 bf1 = *(const short8*)&b_s[(wn * 32 + 16 + l4) * 72 + kh * 32 + quad * 8];
#pragma unroll
            for (int mt = 0; mt < 4; ++mt) {
                short8 af = *(const short8*)&a_s[(wm * 64 + mt * 16 + l4) * 72 + kh * 32 + quad * 8];
                acc[mt][0] = __builtin_amdgcn_mfma_f32_16x16x32_bf16(af, bf0, acc[mt][0], 0, 0, 0);
                acc[mt][1] = __builtin_amdgcn_mfma_f32_16x16x32_bf16(af, bf1, acc[mt][1], 0, 0, 0);
            }
        }
        __syncthreads();
    }
#pragma unroll
    for (int nt = 0; nt < 2; ++nt) {
        int c = n0 + wn * 32 + nt * 16 + l4;
        float bv = bias[c];
#pragma unroll
        for (int mt = 0; mt < 4; ++mt) {
            int mbase = m0 + wm * 64 + mt * 16 + quad * 4;
#pragma unroll
            for (int reg = 0; reg < 4; ++reg)
                out[(size_t)(mbase + reg) * 256 + c] = acc[mt][nt][reg] + bv;
        }
    }
}

extern "C" void kernel_launch(void* const* d_in, const int* in_sizes, int n_in,
                              void* d_out, int out_size, void* d_ws, size_t ws_size,
                              hipStream_t stream)
{
    const float* feats = (const float*)d_in[0];
    const float* nco   = (const float*)d_in[1];
    const float* qkvw  = (const float*)d_in[2];
    const float* qkvb  = (const float*)d_in[3];
    const float* qxt   = (const float*)d_in[4];
    const float* kxt   = (const float*)d_in[5];
    const float* vxt   = (const float*)d_in[6];
    const float* qrt   = (const float*)d_in[7];
    const float* krt   = (const float*)d_in[8];
    const float* vrt   = (const float*)d_in[9];
    const float* pw    = (const float*)d_in[10];
    const float* pb    = (const float*)d_in[11];
    float* out = (float*)d_out;

    ushort* qb  = (ushort*)d_ws;                       // [128][8][64][32]
    ushort* kb  = qb + (size_t)2097152;
    ushort* vb  = kb + (size_t)2097152;
    ushort* aob = vb + (size_t)2097152;                // [8192][256] bf16
    ushort* cst = aob + (size_t)2097152;               // bf16 cast region
    ushort* featsB = cst;                              // 2,097,152 el
    ushort* qkvwB  = cst + (size_t)2097152;            //   196,608 el
    ushort* projwB = cst + (size_t)2293760;            //    65,536 el
    ushort* qxtB   = cst + (size_t)2359296;            //    30,720 el
    ushort* kxtB   = cst + (size_t)2390016;
    ushort* vxtB   = cst + (size_t)2420736;
    ushort* qrtB   = cst + (size_t)2451456;            //    24,576 el
    ushort* krtB   = cst + (size_t)2476032;
    ushort* vrtB   = cst + (size_t)2500608;            // end 2,525,184 el

    k_cast<<<dim3(2466), 256, 0, stream>>>(feats, qkvw, pw, qxt, kxt, vxt, qrt, krt, vrt, cst);
    k_qkv<<<dim3(12, 64), 256, 0, stream>>>(featsB, qkvwB, qkvb, qb, kb, vb);
    k_attn<<<dim3(1024), 256, 0, stream>>>(qb, kb, vb, nco, qxtB, kxtB, vxtB, qrtB, krtB, vrtB, aob);
    k_proj<<<dim3(4, 64), 256, 0, stream>>>(aob, projwB, pb, out);
}